// Round 9
// baseline (1132.363 us; speedup 1.0000x reference)
//
#include <hip/hip_runtime.h>
#include <hip/hip_bf16.h>

typedef unsigned short ushort_t;
typedef __bf16 bf16x8 __attribute__((ext_vector_type(8)));
typedef unsigned short ushort8 __attribute__((ext_vector_type(8)));
typedef unsigned short ushort4v __attribute__((ext_vector_type(4)));
typedef float f32x4 __attribute__((ext_vector_type(4)));

#define HH 128          // hidden dim
#define EPS 1e-5f
#define STAT_SLICES 32
#define MTILE 32        // mm1 tile rows
#define FB 1280         // fused kernel grid: 5 blocks/CU x 256 CU (co-resident by construction)
#define BAR_LINES 32    // hierarchical barrier arrival lines (FB % BAR_LINES == 0)

__device__ __forceinline__ float bf2f(ushort_t u) {
    unsigned v = ((unsigned)u) << 16;
    return __builtin_bit_cast(float, v);
}
__device__ __forceinline__ ushort_t f2bf(float f) {
    unsigned u = __builtin_bit_cast(unsigned, f);
    unsigned r = (u + 0x7fffu + ((u >> 16) & 1u)) >> 16;
    return (ushort_t)r;
}
__device__ __forceinline__ float cvt(const void* p, int i, int flag) {
    return flag ? bf2f(((const ushort_t*)p)[i]) : ((const float*)p)[i];
}
// accumulate 8 bf16 channels (one uint4) scaled by c into a[8]
__device__ __forceinline__ void acc8(const uint4 w, float c, float a[8]) {
    unsigned x0 = w.x, x1 = w.y, x2 = w.z, x3 = w.w;
    a[0] = fmaf(__builtin_bit_cast(float, x0 << 16), c, a[0]);
    a[1] = fmaf(__builtin_bit_cast(float, x0 & 0xffff0000u), c, a[1]);
    a[2] = fmaf(__builtin_bit_cast(float, x1 << 16), c, a[2]);
    a[3] = fmaf(__builtin_bit_cast(float, x1 & 0xffff0000u), c, a[3]);
    a[4] = fmaf(__builtin_bit_cast(float, x2 << 16), c, a[4]);
    a[5] = fmaf(__builtin_bit_cast(float, x2 & 0xffff0000u), c, a[5]);
    a[6] = fmaf(__builtin_bit_cast(float, x3 << 16), c, a[6]);
    a[7] = fmaf(__builtin_bit_cast(float, x3 & 0xffff0000u), c, a[7]);
}

// device-wide barrier, hierarchical arrival + BROADCAST release:
//  - FB blocks -> 32 counter lines (256B apart), FB/32 serialized atomics per line.
//  - line-finishers add to mid; last broadcasts the epoch to 8 release lines.
//  - waiter polls ITS line (bid&7) with RELAXED agent loads (no per-poll invalidate)
//    + coarse s_sleep(32) backoff (~2K cy) -> ~0.01 loads/cy/line, no poll storm.
//  - ONE acquire fence at exit.
__device__ __forceinline__ void gridSync(int* lines, int* mid, int* rel, int phase, int nb) {
    __syncthreads();
    if (threadIdx.x == 0) {
        __threadfence();                       // release: my phase writes visible
        const int per = nb / BAR_LINES;
        int* lp = lines + (blockIdx.x & (BAR_LINES - 1)) * 64;
        int prev = atomicAdd(lp, 1);
        if (prev == per * phase - 1) {
            int pm = atomicAdd(mid, 1);
            if (pm == BAR_LINES * phase - 1) {
#pragma unroll
                for (int k = 0; k < 8; ++k)
                    __hip_atomic_store(rel + k * 64, phase, __ATOMIC_RELEASE, __HIP_MEMORY_SCOPE_AGENT);
            }
        }
        int* myrel = rel + (blockIdx.x & 7) * 64;
        while (__hip_atomic_load(myrel, __ATOMIC_RELAXED, __HIP_MEMORY_SCOPE_AGENT) < phase)
            __builtin_amdgcn_s_sleep(32);
        __threadfence();                       // acquire: invalidate stale caches ONCE
    }
    __syncthreads();
}

// ================= fused pre-kernel: hist | weight-transpose | setup =================
// Wt stored UNPADDED row-major: Wt1[128][256], Wt2/3[128][128]
__global__ void preK(const int* __restrict__ dst, int* __restrict__ counts, int E,
                     const void* W1, ushort_t* Wt1, const void* W2, ushort_t* Wt2,
                     const void* W3, ushort_t* Wt3,
                     const void* g1, const void* b1, const void* b2, const void* b3,
                     const void* g2, const void* g3, const void* be1, const void* be2,
                     const void* be3, const void* Wfp, const void* bfp,
                     float* __restrict__ cvec, int histB) {
    const int bid = blockIdx.x;
    const int tid = threadIdx.x;
    const int flag = (((const ushort_t*)g1)[0] == 0x3F80) ? 1 : 0;
    if (bid < histB) {
        int e = bid * 256 + tid;
        if (e < E) atomicAdd(&counts[dst[e]], 1);
    } else if (bid < histB + 256) {
        int idx = (bid - histB) * 256 + tid;   // 0..65535
        const void* W; ushort_t* Wt; int K;
        if (idx < 32768)      { W = W1; Wt = Wt1; K = 256; }
        else if (idx < 49152) { W = W2; Wt = Wt2; K = 128; idx -= 32768; }
        else                  { W = W3; Wt = Wt3; K = 128; idx -= 49152; }
        int k = idx >> 7, nn = idx & 127;
        Wt[nn * K + k] = flag ? ((const ushort_t*)W)[idx] : f2bf(((const float*)W)[idx]);
    } else {
        int t = tid;
        if (t < 128) {
            cvec[t]        = cvt(b1, t, flag);
            cvec[128 + t]  = cvt(b2, t, flag);
            cvec[256 + t]  = cvt(b3, t, flag);
            cvec[384 + t]  = cvt(g1, t, flag);
            cvec[512 + t]  = cvt(g2, t, flag);
            cvec[640 + t]  = cvt(g3, t, flag);
            cvec[768 + t]  = cvt(be1, t, flag);
            cvec[896 + t]  = cvt(be2, t, flag);
            cvec[1024 + t] = cvt(be3, t, flag);
            cvec[1152 + t] = cvt(Wfp, t, flag);
            if (t == 0) cvec[1280] = cvt(bfp, 0, flag);
        }
    }
}

// ================= fused: scanA (block sums) | disK =================
__global__ void scanAdisK(const int* __restrict__ cnt, int* __restrict__ partial,
                          float* __restrict__ dis, int n, int nbScan) {
    __shared__ int lds[256];
    const int tid = threadIdx.x;
    if ((int)blockIdx.x < nbScan) {
        int base = blockIdx.x * 2048 + tid * 8;
        int s = 0;
#pragma unroll
        for (int j = 0; j < 8; ++j) { int idx = base + j; if (idx < n) s += cnt[idx]; }
        lds[tid] = s; __syncthreads();
        for (int off = 128; off; off >>= 1) { if (tid < off) lds[tid] += lds[tid + off]; __syncthreads(); }
        if (tid == 0) partial[blockIdx.x] = lds[0];
    } else {
        int i = (blockIdx.x - nbScan) * 256 + tid;
        if (i < n) dis[i] = rsqrtf((float)cnt[i] + 1.0f);
    }
}

// scanC with local recompute of the partial prefix
__device__ __forceinline__ void scanC2Dev(int* lds, const int* __restrict__ cnt,
                                          const int* __restrict__ partial,
                                          int* __restrict__ rowptr, int n, int bid, int nb) {
    const int tid = threadIdx.x;
    int pre = 0, tot = 0;
    for (int i = 0; i < nb; ++i) { int v = partial[i]; if (i < bid) pre += v; tot += v; }
    int base = bid * 2048 + tid * 8;
    int v[8]; int s = 0;
#pragma unroll
    for (int j = 0; j < 8; ++j) { int idx = base + j; v[j] = (idx < n) ? cnt[idx] : 0; s += v[j]; }
    lds[tid] = s; __syncthreads();
    for (int off = 1; off < 256; off <<= 1) {
        int x = (tid >= off) ? lds[tid - off] : 0;
        __syncthreads();
        lds[tid] += x;
        __syncthreads();
    }
    int excl = lds[tid] - s;
    int off0 = pre + excl;
#pragma unroll
    for (int j = 0; j < 8; ++j) {
        int idx = base + j;
        if (idx < n) { rowptr[idx] = off0; off0 += v[j]; }
    }
    if (bid == 0 && tid == 0) rowptr[n] = tot;
}

// ================= mm layer1 (K=256): W in REGISTERS, cooperative bf16 A staging ======
__global__ __launch_bounds__(256) void mm1scanCK(const void* __restrict__ x,
                                                 const ushort_t* __restrict__ Wt1,
                                                 ushort_t* __restrict__ tbuf, int n,
                                                 const ushort_t* __restrict__ flagRef,
                                                 const int* __restrict__ cnt,
                                                 const int* __restrict__ partial,
                                                 int* __restrict__ rowptr, int nbScan) {
    __shared__ char smem[33792];           // 2 x 16KB A bufs | scanC scratch (1KB)
    const int tid = threadIdx.x;
    if ((int)blockIdx.x < nbScan) {
        scanC2Dev((int*)smem, cnt, partial, rowptr, n, blockIdx.x, nbScan);
        return;
    }
    const int arm = blockIdx.x - nbScan;
    const int NB  = gridDim.x - nbScan;
    const int nTiles = (n + MTILE - 1) / MTILE;
    if (arm >= nTiles) return;

    const int lane = tid & 63, wave = tid >> 6;
    const int m = lane & 15, q = lane >> 4;
    const int flag = (flagRef[0] == 0x3F80) ? 1 : 0;

    // ---- W fragments in registers: wave w covers out-ch groups t = 2w, 2w+1
    ushort8 wfrag[8][2];
#pragma unroll
    for (int s = 0; s < 8; ++s)
#pragma unroll
        for (int tt = 0; tt < 2; ++tt)
            wfrag[s][tt] = *(const ushort8*)&Wt1[(size_t)((wave * 2 + tt) * 16 + m) * 256 + s * 32 + q * 8];

    // staging thread mapping: row sr (0..31), 32 cols starting at sa*32
    const int sr = tid >> 3, sa = tid & 7;
    char* buf0 = smem;
    char* buf1 = smem + 16384;

    float4  f[8];
    ushort8 v[4];

    auto stageLoad = [&](int T) {
        int row = T * MTILE + sr; if (row >= n) row = n - 1;
        if (flag) {
            const ushort_t* xp = (const ushort_t*)x + (size_t)row * 256 + sa * 32;
#pragma unroll
            for (int j = 0; j < 4; ++j) v[j] = *(const ushort8*)(xp + j * 8);
        } else {
            const float* xp = (const float*)x + (size_t)row * 256 + sa * 32;
#pragma unroll
            for (int j = 0; j < 8; ++j) f[j] = *(const float4*)(xp + j * 4);
        }
    };
    auto convWrite = [&](char* buf) {
        if (!flag) {
#pragma unroll
            for (int j = 0; j < 4; ++j) {
                float4 a = f[2 * j], b = f[2 * j + 1];
                ushort8 t8;
                t8[0] = f2bf(a.x); t8[1] = f2bf(a.y); t8[2] = f2bf(a.z); t8[3] = f2bf(a.w);
                t8[4] = f2bf(b.x); t8[5] = f2bf(b.y); t8[6] = f2bf(b.z); t8[7] = f2bf(b.w);
                v[j] = t8;
            }
        }
#pragma unroll
        for (int j = 0; j < 4; ++j) {
            int u = (sa * 4 + j) ^ (sr & 7);
            *(ushort8*)(buf + sr * 512 + u * 16) = v[j];
        }
    };
    auto computeStore = [&](int T, const char* buf) {
        f32x4 acc[2][2];
#pragma unroll
        for (int bb = 0; bb < 2; ++bb)
#pragma unroll
            for (int tt = 0; tt < 2; ++tt) acc[bb][tt] = (f32x4){0.f, 0.f, 0.f, 0.f};
#pragma unroll
        for (int bb = 0; bb < 2; ++bb) {
            const char* base = buf + (bb * 16 + m) * 512;
#pragma unroll
            for (int s = 0; s < 8; ++s) {
                ushort8 xf = *(const ushort8*)(base + (((s * 4 + q) ^ (m & 7)) * 16));
                bf16x8 xb = __builtin_bit_cast(bf16x8, xf);
#pragma unroll
                for (int tt = 0; tt < 2; ++tt)
                    acc[bb][tt] = __builtin_amdgcn_mfma_f32_16x16x32_bf16(
                        __builtin_bit_cast(bf16x8, wfrag[s][tt]), xb, acc[bb][tt], 0, 0, 0);
            }
        }
#pragma unroll
        for (int bb = 0; bb < 2; ++bb) {
            int node = T * MTILE + bb * 16 + m;
            if (node < n) {
#pragma unroll
                for (int tt = 0; tt < 2; ++tt) {
                    ushort4v pk;
#pragma unroll
                    for (int r = 0; r < 4; ++r) pk[r] = f2bf(acc[bb][tt][r]);
                    *(ushort4v*)(tbuf + (size_t)node * HH + (wave * 2 + tt) * 16 + q * 4) = pk;
                }
            }
        }
    };

    // prologue
    stageLoad(arm); convWrite(buf0);
    __syncthreads();
    int T = arm, pp = 0;
    while (true) {
        int Tn = T + NB;
        bool more = (Tn < nTiles);
        if (more) stageLoad(Tn);               // issue next-tile loads early
        computeStore(T, pp ? buf1 : buf0);     // hide load latency under MFMAs
        if (!more) break;
        convWrite(pp ? buf0 : buf1);
        __syncthreads();
        T = Tn; pp ^= 1;
    }
}

// ================= fused post-mm1 chain: scatter|agg1|mm2|agg2|mm3|agg3|out ===========
// One kernel, 6 device-wide barriers. 1280 blocks x 256 thr, 5 blocks/CU co-resident.
// launch_bounds(256,5) -> VGPR cap 102 (r8's cap of 64 forced scratch spills in the
// agg gather loop: VGPR_Count was pinned at exactly 64). LDS 17.4KB x5 = 87KB/CU.
__global__ __launch_bounds__(256, 5) void fusedK(
        const int* __restrict__ src, const int* __restrict__ dst,
        const int* __restrict__ rowptr, int* __restrict__ fill,
        const float* __restrict__ dis, uint2* __restrict__ erec, int E,
        const ushort_t* __restrict__ Wt2, const ushort_t* __restrict__ Wt3,
        ushort_t* __restrict__ tbuf, ushort_t* __restrict__ gbuf,
        const float* __restrict__ cvec, float* __restrict__ stats,
        void* __restrict__ outv, int n, const ushort_t* __restrict__ flagRef,
        int* __restrict__ blines, int* __restrict__ bmid, int* __restrict__ brel) {
    __shared__ char smem[17408];           // mm: 2x8KB A dbuf + 1KB scw | agg: 4KB red
    const int NB  = gridDim.x;
    const int tid = threadIdx.x;
    const int lane = tid & 63, wave = tid >> 6;

    const float* c_b1  = cvec;        const float* c_b2  = cvec + 128;
    const float* c_b3  = cvec + 256;  const float* c_g1  = cvec + 384;
    const float* c_g2  = cvec + 512;  const float* c_g3  = cvec + 640;
    const float* c_be1 = cvec + 768;  const float* c_be2 = cvec + 896;
    const float* c_be3 = cvec + 1024; const float* c_Wf  = cvec + 1152;
    const float* c_bf  = cvec + 1280;
    float* ssum0 = stats;            float* ssq0 = stats + 4096;
    float* ssum1 = stats + 8192;     float* ssq1 = stats + 12288;
    float* ssum2 = stats + 16384;    float* ssq2 = stats + 20480;

    // ---------------- P0: CSR scatter ----------------
    for (int e = blockIdx.x * 256 + tid; e < E; e += NB * 256) {
        int d = dst[e], s = src[e];
        int old = atomicSub(&fill[d], 1);
        int pos = rowptr[d] + old - 1;
        float c = dis[s] * dis[d];
        uint2 r; r.x = (unsigned)s; r.y = __builtin_bit_cast(unsigned, c);
        erec[pos] = r;
    }

    // ---------------- agg phase (t -> g, bias, stats) ----------------
    auto aggPhase = [&](const ushort_t* __restrict__ t, ushort_t* __restrict__ g,
                        const float* __restrict__ bias,
                        float* __restrict__ ssum, float* __restrict__ ssq) {
        const int grp = lane >> 4, p = lane & 15, cb = p * 8;
        float bch[8];
#pragma unroll
        for (int j = 0; j < 8; ++j) bch[j] = bias[cb + j];
        float s[8], q[8];
#pragma unroll
        for (int j = 0; j < 8; ++j) { s[j] = 0.f; q[j] = 0.f; }

        for (int node = blockIdx.x * 16 + wave * 4 + grp; node < n; node += NB * 16) {
            float d = dis[node];
            float d2 = d * d;
            float a[8];
#pragma unroll
            for (int j = 0; j < 8; ++j) a[j] = 0.f;
            uint4 sv = *(const uint4*)(t + (size_t)node * HH + cb);
            acc8(sv, d2, a);

            const int beg = rowptr[node], end = rowptr[node + 1];
            int e = beg;
            for (; e + 8 <= end; e += 8) {
                uint2 rr[8];
#pragma unroll
                for (int kk = 0; kk < 8; ++kk) rr[kk] = erec[e + kk];
                uint4 w0[4];
#pragma unroll
                for (int kk = 0; kk < 4; ++kk)
                    w0[kk] = *(const uint4*)(t + (size_t)rr[kk].x * HH + cb);
                uint4 w1[4];
#pragma unroll
                for (int kk = 0; kk < 4; ++kk)
                    w1[kk] = *(const uint4*)(t + (size_t)rr[4 + kk].x * HH + cb);
#pragma unroll
                for (int kk = 0; kk < 4; ++kk)
                    acc8(w0[kk], __builtin_bit_cast(float, rr[kk].y), a);
#pragma unroll
                for (int kk = 0; kk < 4; ++kk)
                    acc8(w1[kk], __builtin_bit_cast(float, rr[4 + kk].y), a);
            }
            if (e < end) {
                uint2 rr[8];
#pragma unroll
                for (int kk = 0; kk < 8; ++kk) {
                    int idx = e + kk;
                    rr[kk] = (idx < end) ? erec[idx] : (uint2){0u, 0u};
                }
                uint4 w0[4];
#pragma unroll
                for (int kk = 0; kk < 4; ++kk)
                    w0[kk] = *(const uint4*)(t + (size_t)rr[kk].x * HH + cb);
                uint4 w1[4];
#pragma unroll
                for (int kk = 0; kk < 4; ++kk)
                    w1[kk] = *(const uint4*)(t + (size_t)rr[4 + kk].x * HH + cb);
#pragma unroll
                for (int kk = 0; kk < 4; ++kk)
                    acc8(w0[kk], __builtin_bit_cast(float, rr[kk].y), a);
#pragma unroll
                for (int kk = 0; kk < 4; ++kk)
                    acc8(w1[kk], __builtin_bit_cast(float, rr[4 + kk].y), a);
            }

            ushort8 pk;
#pragma unroll
            for (int j = 0; j < 8; ++j) {
                a[j] += bch[j];
                pk[j] = f2bf(a[j]);
                s[j] += a[j]; q[j] += a[j] * a[j];
            }
            *(ushort8*)(g + (size_t)node * HH + cb) = pk;
        }

#pragma unroll
        for (int j = 0; j < 8; ++j) {
            s[j] += __shfl_xor(s[j], 16); s[j] += __shfl_xor(s[j], 32);
            q[j] += __shfl_xor(q[j], 16); q[j] += __shfl_xor(q[j], 32);
        }
        float (*red)[16][16] = (float (*)[16][16])smem;
        __syncthreads();                       // smem free from prior phase
        if (grp == 0) {
#pragma unroll
            for (int j = 0; j < 8; ++j) { red[wave][p][j] = s[j]; red[wave][p][8 + j] = q[j]; }
        }
        __syncthreads();
        {
            int ch = tid & 127, kind = tid >> 7;
            float S = 0.f;
#pragma unroll
            for (int w = 0; w < 4; ++w) S += red[w][ch >> 3][kind * 8 + (ch & 7)];
            int slice = (blockIdx.x & (STAT_SLICES - 1)) * HH;
            atomicAdd((kind ? ssq : ssum) + slice + ch, S);
        }
    };

    // ---------------- mm+BN phase (A -> out, K=128, W in regs) ----------------
    auto mmPhase = [&](const ushort_t* __restrict__ A, const ushort_t* __restrict__ Wt,
                       ushort_t* __restrict__ out,
                       const float* __restrict__ ssum, const float* __restrict__ ssq,
                       const float* __restrict__ gam, const float* __restrict__ bet) {
        float* scw = (float*)(smem + 16384);
        if (tid < 128) {
            float S = 0.f, Q = 0.f;
#pragma unroll
            for (int sl = 0; sl < STAT_SLICES; ++sl) { S += ssum[sl * HH + tid]; Q += ssq[sl * HH + tid]; }
            float invn = 1.0f / (float)n;
            float mu = S * invn;
            float var = fmaxf(Q * invn - mu * mu, 0.f);
            float sc = gam[tid] * rsqrtf(var + EPS);
            scw[tid] = sc;
            scw[128 + tid] = bet[tid] - mu * sc;
        }
        const int m = lane & 15, q4 = lane >> 4;
        ushort8 wfrag[4][2];
#pragma unroll
        for (int s = 0; s < 4; ++s)
#pragma unroll
            for (int tt = 0; tt < 2; ++tt)
                wfrag[s][tt] = *(const ushort8*)&Wt[(size_t)((wave * 2 + tt) * 16 + m) * 128 + s * 32 + q4 * 8];

        const int sr = tid >> 3, sa = tid & 7;   // stage: row sr (0..31), 32B block sa
        char* b0 = smem;
        char* b1 = smem + 8192;
        ushort8 sv[2];

        auto sLoad = [&](int T) {
            int row = T * 32 + sr; if (row >= n) row = n - 1;
            const ushort_t* ap = A + (size_t)row * HH + sa * 16;
            sv[0] = *(const ushort8*)ap;
            sv[1] = *(const ushort8*)(ap + 8);
        };
        auto sWrite = [&](char* buf) {
#pragma unroll
            for (int j = 0; j < 2; ++j) {
                int u = (sa * 2 + j) ^ (sr & 7);
                *(ushort8*)(buf + sr * 256 + u * 16) = sv[j];
            }
        };
        auto comp = [&](int T, const char* buf) {
            f32x4 acc[2][2];
#pragma unroll
            for (int bb = 0; bb < 2; ++bb)
#pragma unroll
                for (int tt = 0; tt < 2; ++tt) acc[bb][tt] = (f32x4){0.f, 0.f, 0.f, 0.f};
#pragma unroll
            for (int bb = 0; bb < 2; ++bb) {
                const char* arow = buf + (bb * 16 + m) * 256;
#pragma unroll
                for (int s = 0; s < 4; ++s) {
                    ushort8 av = *(const ushort8*)(arow + (((s * 4 + q4) ^ (m & 7)) * 16));
                    int kb = s * 32 + q4 * 8;
#pragma unroll
                    for (int j = 0; j < 8; ++j)
                        av[j] = f2bf(fmaxf(bf2f(av[j]) * scw[kb + j] + scw[128 + kb + j], 0.f));
                    bf16x8 nf = __builtin_bit_cast(bf16x8, av);
#pragma unroll
                    for (int tt = 0; tt < 2; ++tt)
                        acc[bb][tt] = __builtin_amdgcn_mfma_f32_16x16x32_bf16(
                            __builtin_bit_cast(bf16x8, wfrag[s][tt]), nf, acc[bb][tt], 0, 0, 0);
                }
            }
#pragma unroll
            for (int bb = 0; bb < 2; ++bb) {
                int node = T * 32 + bb * 16 + m;
                if (node < n) {
#pragma unroll
                    for (int tt = 0; tt < 2; ++tt) {
                        ushort4v pk;
#pragma unroll
                        for (int r = 0; r < 4; ++r) pk[r] = f2bf(acc[bb][tt][r]);
                        *(ushort4v*)(out + (size_t)node * HH + (wave * 2 + tt) * 16 + q4 * 4) = pk;
                    }
                }
            }
        };

        const int nT = (n + 31) >> 5;
        int T = blockIdx.x, pp = 0;
        if (T < nT) sLoad(T);
        __syncthreads();                       // scw ready; smem free from prior phase
        if (T < nT) sWrite(b0);
        __syncthreads();
        while (T < nT) {
            int Tn = T + NB;
            if (Tn < nT) sLoad(Tn);
            comp(T, pp ? b1 : b0);
            if (Tn >= nT) break;
            sWrite(pp ? b0 : b1);
            __syncthreads();
            T = Tn; pp ^= 1;
        }
    };

    // ---------------- phase chain ----------------
    gridSync(blines, bmid, brel, 1, NB);
    aggPhase(tbuf, gbuf, c_b1, ssum0, ssq0);
    gridSync(blines, bmid, brel, 2, NB);
    mmPhase(gbuf, Wt2, tbuf, ssum0, ssq0, c_g1, c_be1);
    gridSync(blines, bmid, brel, 3, NB);
    aggPhase(tbuf, gbuf, c_b2, ssum1, ssq1);
    gridSync(blines, bmid, brel, 4, NB);
    mmPhase(gbuf, Wt3, tbuf, ssum1, ssq1, c_g2, c_be2);
    gridSync(blines, bmid, brel, 5, NB);
    aggPhase(tbuf, gbuf, c_b3, ssum2, ssq2);
    gridSync(blines, bmid, brel, 6, NB);

    // ---------------- P6: output head ----------------
    {
        float* scw = (float*)(smem + 16384);
        if (tid < 128) {
            float S = 0.f, Q = 0.f;
#pragma unroll
            for (int sl = 0; sl < STAT_SLICES; ++sl) { S += ssum2[sl * HH + tid]; Q += ssq2[sl * HH + tid]; }
            float invn = 1.0f / (float)n;
            float mu = S * invn;
            float var = fmaxf(Q * invn - mu * mu, 0.f);
            float sc = c_g3[tid] * rsqrtf(var + EPS);
            scw[tid] = sc;
            scw[128 + tid] = c_be3[tid] - mu * sc;
        }
        __syncthreads();

        const int grp = lane >> 4, p = lane & 15, cb = p * 8;
        float w8[8], sc8[8], sh8[8];
#pragma unroll
        for (int j = 0; j < 8; ++j) {
            w8[j] = c_Wf[cb + j]; sc8[j] = scw[cb + j]; sh8[j] = scw[128 + cb + j];
        }
        const float bb = c_bf[0];
        const int flag = (flagRef[0] == 0x3F80) ? 1 : 0;

        for (int node = blockIdx.x * 16 + wave * 4 + grp; node < n; node += NB * 16) {
            uint4 v = *(const uint4*)(gbuf + (size_t)node * HH + cb);
            unsigned u[4] = {v.x, v.y, v.z, v.w};
            float x = 0.f;
#pragma unroll
            for (int j = 0; j < 4; ++j) {
                float f0 = __builtin_bit_cast(float, u[j] << 16);
                float f1 = __builtin_bit_cast(float, u[j] & 0xffff0000u);
                x += fmaxf(f0 * sc8[2 * j] + sh8[2 * j], 0.f) * w8[2 * j];
                x += fmaxf(f1 * sc8[2 * j + 1] + sh8[2 * j + 1], 0.f) * w8[2 * j + 1];
            }
#pragma unroll
            for (int off = 8; off; off >>= 1) x += __shfl_xor(x, off);
            if (p == 0) {
                float r = x + bb;
                if (flag) ((ushort_t*)outv)[node] = f2bf(r);
                else      ((float*)outv)[node] = r;
            }
        }
    }
}

// ================= launch =================
extern "C" void kernel_launch(void* const* d_in, const int* in_sizes, int n_in,
                              void* d_out, int out_size, void* d_ws, size_t ws_size,
                              hipStream_t stream) {
    const int DIN = 256;
    const int N = in_sizes[0] / DIN;
    const int E = in_sizes[1];

    const void* x   = d_in[0];
    const int*  src = (const int*)d_in[1];
    const int*  dst = (const int*)d_in[2];
    const void* W1  = d_in[3];
    const void* b1  = d_in[4];
    const void* g1  = d_in[5];
    const void* be1 = d_in[6];
    const void* W2  = d_in[7];
    const void* b2  = d_in[8];
    const void* g2  = d_in[9];
    const void* be2 = d_in[10];
    const void* W3  = d_in[11];
    const void* b3  = d_in[12];
    const void* g3  = d_in[13];
    const void* be3 = d_in[14];
    const void* Wf  = d_in[15];
    const void* bfp = d_in[16];
    const ushort_t* flagRef = (const ushort_t*)g1;

    char* base = (char*)d_ws;
    size_t off = 0;
    auto carve = [&](size_t bytes) -> void* {
        void* p = base + off;
        off += (bytes + 255) & ~(size_t)255;
        return p;
    };
    int*      counts = (int*)carve((size_t)N * 4);
    float*    stats  = (float*)carve((size_t)3 * 2 * STAT_SLICES * HH * 4);
    int*      bar    = (int*)carve((size_t)(BAR_LINES * 64 + 64 + 8 * 64) * 4); // lines | mid | rel[8]
    size_t    zbytes = off;                       // memset range [0, zbytes)
    float*    dis    = (float*)carve((size_t)N * 4);
    int*      rowptr = (int*)carve((size_t)(N + 1) * 4);
    int*      partial= (int*)carve(256 * 4);
    uint2*    erec   = (uint2*)carve((size_t)E * 8);
    ushort_t* Wt1    = (ushort_t*)carve((size_t)128 * 256 * 2);
    ushort_t* Wt2    = (ushort_t*)carve((size_t)128 * 128 * 2);
    ushort_t* Wt3    = (ushort_t*)carve((size_t)128 * 128 * 2);
    ushort_t* tbuf   = (ushort_t*)carve((size_t)N * HH * 2);
    ushort_t* gbuf   = (ushort_t*)carve((size_t)N * HH * 2);
    float*    cvec   = (float*)carve((size_t)1281 * 4);

    const int nbScan = (N + 2047) / 2048;
    const int histB  = (E + 255) / 256;
    const int disB   = (N + 255) / 256;
    const int mm1B   = 1024;

    hipMemsetAsync(d_ws, 0, zbytes, stream);   // counts + stats + barrier

    preK<<<histB + 256 + 1, 256, 0, stream>>>(dst, counts, E, W1, Wt1, W2, Wt2, W3, Wt3,
                                              g1, b1, b2, b3, g2, g3, be1, be2, be3, Wf, bfp,
                                              cvec, histB);
    scanAdisK<<<nbScan + disB, 256, 0, stream>>>(counts, partial, dis, N, nbScan);
    mm1scanCK<<<nbScan + mm1B, 256, 0, stream>>>(x, Wt1, tbuf, N, flagRef,
                                                 counts, partial, rowptr, nbScan);
    fusedK<<<FB, 256, 0, stream>>>(src, dst, rowptr, counts, dis, erec, E,
                                   Wt2, Wt3, tbuf, gbuf, cvec, stats,
                                   d_out, N, flagRef,
                                   bar, bar + BAR_LINES * 64, bar + BAR_LINES * 64 + 64);
}

// Round 10
// 813.904 us; speedup vs baseline: 1.3913x; 1.3913x over previous
//
#include <hip/hip_runtime.h>
#include <hip/hip_bf16.h>

typedef unsigned short ushort_t;
typedef __bf16 bf16x8 __attribute__((ext_vector_type(8)));
typedef unsigned short ushort8 __attribute__((ext_vector_type(8)));
typedef unsigned short ushort4v __attribute__((ext_vector_type(4)));
typedef float f32x4 __attribute__((ext_vector_type(4)));

#define HH 128          // hidden dim
#define EPS 1e-5f
#define STAT_SLICES 32
#define MTILE 32        // mm1 tile rows
#define FB 1024         // fused kernel grid: 4 blocks/CU x 256 CU (co-resident by construction)
#define BAR_LINES 32    // hierarchical barrier arrival lines (FB % BAR_LINES == 0)

__device__ __forceinline__ float bf2f(ushort_t u) {
    unsigned v = ((unsigned)u) << 16;
    return __builtin_bit_cast(float, v);
}
__device__ __forceinline__ ushort_t f2bf(float f) {
    unsigned u = __builtin_bit_cast(unsigned, f);
    unsigned r = (u + 0x7fffu + ((u >> 16) & 1u)) >> 16;
    return (ushort_t)r;
}
__device__ __forceinline__ float cvt(const void* p, int i, int flag) {
    return flag ? bf2f(((const ushort_t*)p)[i]) : ((const float*)p)[i];
}
// accumulate 8 bf16 channels (one uint4) scaled by c into a[8]
__device__ __forceinline__ void acc8(const uint4 w, float c, float a[8]) {
    unsigned x0 = w.x, x1 = w.y, x2 = w.z, x3 = w.w;
    a[0] = fmaf(__builtin_bit_cast(float, x0 << 16), c, a[0]);
    a[1] = fmaf(__builtin_bit_cast(float, x0 & 0xffff0000u), c, a[1]);
    a[2] = fmaf(__builtin_bit_cast(float, x1 << 16), c, a[2]);
    a[3] = fmaf(__builtin_bit_cast(float, x1 & 0xffff0000u), c, a[3]);
    a[4] = fmaf(__builtin_bit_cast(float, x2 << 16), c, a[4]);
    a[5] = fmaf(__builtin_bit_cast(float, x2 & 0xffff0000u), c, a[5]);
    a[6] = fmaf(__builtin_bit_cast(float, x3 << 16), c, a[6]);
    a[7] = fmaf(__builtin_bit_cast(float, x3 & 0xffff0000u), c, a[7]);
}

// device-wide barrier, hierarchical arrival + BROADCAST release (r8-proven):
//  - FB blocks -> 32 counter lines (256B apart), FB/32 serialized atomics per line.
//  - line-finishers add to mid; last broadcasts the epoch to 8 release lines.
//  - waiter polls ITS line (bid&7) with RELAXED agent loads + s_sleep(32) backoff.
//  - ONE acquire fence at exit.
__device__ __forceinline__ void gridSync(int* lines, int* mid, int* rel, int phase, int nb) {
    __syncthreads();
    if (threadIdx.x == 0) {
        __threadfence();                       // release: my phase writes visible
        const int per = nb / BAR_LINES;
        int* lp = lines + (blockIdx.x & (BAR_LINES - 1)) * 64;
        int prev = atomicAdd(lp, 1);
        if (prev == per * phase - 1) {
            int pm = atomicAdd(mid, 1);
            if (pm == BAR_LINES * phase - 1) {
#pragma unroll
                for (int k = 0; k < 8; ++k)
                    __hip_atomic_store(rel + k * 64, phase, __ATOMIC_RELEASE, __HIP_MEMORY_SCOPE_AGENT);
            }
        }
        int* myrel = rel + (blockIdx.x & 7) * 64;
        while (__hip_atomic_load(myrel, __ATOMIC_RELAXED, __HIP_MEMORY_SCOPE_AGENT) < phase)
            __builtin_amdgcn_s_sleep(32);
        __threadfence();                       // acquire: invalidate stale caches ONCE
    }
    __syncthreads();
}

// ================= fused pre-kernel: hist | weight-transpose | setup =================
// Wt stored UNPADDED row-major: Wt1[128][256], Wt2/3[128][128]
__global__ void preK(const int* __restrict__ dst, int* __restrict__ counts, int E,
                     const void* W1, ushort_t* Wt1, const void* W2, ushort_t* Wt2,
                     const void* W3, ushort_t* Wt3,
                     const void* g1, const void* b1, const void* b2, const void* b3,
                     const void* g2, const void* g3, const void* be1, const void* be2,
                     const void* be3, const void* Wfp, const void* bfp,
                     float* __restrict__ cvec, int histB) {
    const int bid = blockIdx.x;
    const int tid = threadIdx.x;
    const int flag = (((const ushort_t*)g1)[0] == 0x3F80) ? 1 : 0;
    if (bid < histB) {
        int e = bid * 256 + tid;
        if (e < E) atomicAdd(&counts[dst[e]], 1);
    } else if (bid < histB + 256) {
        int idx = (bid - histB) * 256 + tid;   // 0..65535
        const void* W; ushort_t* Wt; int K;
        if (idx < 32768)      { W = W1; Wt = Wt1; K = 256; }
        else if (idx < 49152) { W = W2; Wt = Wt2; K = 128; idx -= 32768; }
        else                  { W = W3; Wt = Wt3; K = 128; idx -= 49152; }
        int k = idx >> 7, nn = idx & 127;
        Wt[nn * K + k] = flag ? ((const ushort_t*)W)[idx] : f2bf(((const float*)W)[idx]);
    } else {
        int t = tid;
        if (t < 128) {
            cvec[t]        = cvt(b1, t, flag);
            cvec[128 + t]  = cvt(b2, t, flag);
            cvec[256 + t]  = cvt(b3, t, flag);
            cvec[384 + t]  = cvt(g1, t, flag);
            cvec[512 + t]  = cvt(g2, t, flag);
            cvec[640 + t]  = cvt(g3, t, flag);
            cvec[768 + t]  = cvt(be1, t, flag);
            cvec[896 + t]  = cvt(be2, t, flag);
            cvec[1024 + t] = cvt(be3, t, flag);
            cvec[1152 + t] = cvt(Wfp, t, flag);
            if (t == 0) cvec[1280] = cvt(bfp, 0, flag);
        }
    }
}

// ================= fused: scanA (block sums) | disK =================
__global__ void scanAdisK(const int* __restrict__ cnt, int* __restrict__ partial,
                          float* __restrict__ dis, int n, int nbScan) {
    __shared__ int lds[256];
    const int tid = threadIdx.x;
    if ((int)blockIdx.x < nbScan) {
        int base = blockIdx.x * 2048 + tid * 8;
        int s = 0;
#pragma unroll
        for (int j = 0; j < 8; ++j) { int idx = base + j; if (idx < n) s += cnt[idx]; }
        lds[tid] = s; __syncthreads();
        for (int off = 128; off; off >>= 1) { if (tid < off) lds[tid] += lds[tid + off]; __syncthreads(); }
        if (tid == 0) partial[blockIdx.x] = lds[0];
    } else {
        int i = (blockIdx.x - nbScan) * 256 + tid;
        if (i < n) dis[i] = rsqrtf((float)cnt[i] + 1.0f);
    }
}

// scanC with local recompute of the partial prefix
__device__ __forceinline__ void scanC2Dev(int* lds, const int* __restrict__ cnt,
                                          const int* __restrict__ partial,
                                          int* __restrict__ rowptr, int n, int bid, int nb) {
    const int tid = threadIdx.x;
    int pre = 0, tot = 0;
    for (int i = 0; i < nb; ++i) { int v = partial[i]; if (i < bid) pre += v; tot += v; }
    int base = bid * 2048 + tid * 8;
    int v[8]; int s = 0;
#pragma unroll
    for (int j = 0; j < 8; ++j) { int idx = base + j; v[j] = (idx < n) ? cnt[idx] : 0; s += v[j]; }
    lds[tid] = s; __syncthreads();
    for (int off = 1; off < 256; off <<= 1) {
        int x = (tid >= off) ? lds[tid - off] : 0;
        __syncthreads();
        lds[tid] += x;
        __syncthreads();
    }
    int excl = lds[tid] - s;
    int off0 = pre + excl;
#pragma unroll
    for (int j = 0; j < 8; ++j) {
        int idx = base + j;
        if (idx < n) { rowptr[idx] = off0; off0 += v[j]; }
    }
    if (bid == 0 && tid == 0) rowptr[n] = tot;
}

// ================= mm layer1 (K=256): W in REGISTERS, cooperative bf16 A staging ======
__global__ __launch_bounds__(256) void mm1scanCK(const void* __restrict__ x,
                                                 const ushort_t* __restrict__ Wt1,
                                                 ushort_t* __restrict__ tbuf, int n,
                                                 const ushort_t* __restrict__ flagRef,
                                                 const int* __restrict__ cnt,
                                                 const int* __restrict__ partial,
                                                 int* __restrict__ rowptr, int nbScan) {
    __shared__ char smem[33792];           // 2 x 16KB A bufs | scanC scratch (1KB)
    const int tid = threadIdx.x;
    if ((int)blockIdx.x < nbScan) {
        scanC2Dev((int*)smem, cnt, partial, rowptr, n, blockIdx.x, nbScan);
        return;
    }
    const int arm = blockIdx.x - nbScan;
    const int NB  = gridDim.x - nbScan;
    const int nTiles = (n + MTILE - 1) / MTILE;
    if (arm >= nTiles) return;

    const int lane = tid & 63, wave = tid >> 6;
    const int m = lane & 15, q = lane >> 4;
    const int flag = (flagRef[0] == 0x3F80) ? 1 : 0;

    // ---- W fragments in registers: wave w covers out-ch groups t = 2w, 2w+1
    ushort8 wfrag[8][2];
#pragma unroll
    for (int s = 0; s < 8; ++s)
#pragma unroll
        for (int tt = 0; tt < 2; ++tt)
            wfrag[s][tt] = *(const ushort8*)&Wt1[(size_t)((wave * 2 + tt) * 16 + m) * 256 + s * 32 + q * 8];

    // staging thread mapping: row sr (0..31), 32 cols starting at sa*32
    const int sr = tid >> 3, sa = tid & 7;
    char* buf0 = smem;
    char* buf1 = smem + 16384;

    float4  f[8];
    ushort8 v[4];

    auto stageLoad = [&](int T) {
        int row = T * MTILE + sr; if (row >= n) row = n - 1;
        if (flag) {
            const ushort_t* xp = (const ushort_t*)x + (size_t)row * 256 + sa * 32;
#pragma unroll
            for (int j = 0; j < 4; ++j) v[j] = *(const ushort8*)(xp + j * 8);
        } else {
            const float* xp = (const float*)x + (size_t)row * 256 + sa * 32;
#pragma unroll
            for (int j = 0; j < 8; ++j) f[j] = *(const float4*)(xp + j * 4);
        }
    };
    auto convWrite = [&](char* buf) {
        if (!flag) {
#pragma unroll
            for (int j = 0; j < 4; ++j) {
                float4 a = f[2 * j], b = f[2 * j + 1];
                ushort8 t8;
                t8[0] = f2bf(a.x); t8[1] = f2bf(a.y); t8[2] = f2bf(a.z); t8[3] = f2bf(a.w);
                t8[4] = f2bf(b.x); t8[5] = f2bf(b.y); t8[6] = f2bf(b.z); t8[7] = f2bf(b.w);
                v[j] = t8;
            }
        }
#pragma unroll
        for (int j = 0; j < 4; ++j) {
            int u = (sa * 4 + j) ^ (sr & 7);
            *(ushort8*)(buf + sr * 512 + u * 16) = v[j];
        }
    };
    auto computeStore = [&](int T, const char* buf) {
        f32x4 acc[2][2];
#pragma unroll
        for (int bb = 0; bb < 2; ++bb)
#pragma unroll
            for (int tt = 0; tt < 2; ++tt) acc[bb][tt] = (f32x4){0.f, 0.f, 0.f, 0.f};
#pragma unroll
        for (int bb = 0; bb < 2; ++bb) {
            const char* base = buf + (bb * 16 + m) * 512;
#pragma unroll
            for (int s = 0; s < 8; ++s) {
                ushort8 xf = *(const ushort8*)(base + (((s * 4 + q) ^ (m & 7)) * 16));
                bf16x8 xb = __builtin_bit_cast(bf16x8, xf);
#pragma unroll
                for (int tt = 0; tt < 2; ++tt)
                    acc[bb][tt] = __builtin_amdgcn_mfma_f32_16x16x32_bf16(
                        __builtin_bit_cast(bf16x8, wfrag[s][tt]), xb, acc[bb][tt], 0, 0, 0);
            }
        }
#pragma unroll
        for (int bb = 0; bb < 2; ++bb) {
            int node = T * MTILE + bb * 16 + m;
            if (node < n) {
#pragma unroll
                for (int tt = 0; tt < 2; ++tt) {
                    ushort4v pk;
#pragma unroll
                    for (int r = 0; r < 4; ++r) pk[r] = f2bf(acc[bb][tt][r]);
                    *(ushort4v*)(tbuf + (size_t)node * HH + (wave * 2 + tt) * 16 + q * 4) = pk;
                }
            }
        }
    };

    // prologue
    stageLoad(arm); convWrite(buf0);
    __syncthreads();
    int T = arm, pp = 0;
    while (true) {
        int Tn = T + NB;
        bool more = (Tn < nTiles);
        if (more) stageLoad(Tn);               // issue next-tile loads early
        computeStore(T, pp ? buf1 : buf0);     // hide load latency under MFMAs
        if (!more) break;
        convWrite(pp ? buf0 : buf1);
        __syncthreads();
        T = Tn; pp ^= 1;
    }
}

// ================= fused post-mm1 chain: scatter|agg1|mm2|agg2|mm3|agg3|out ===========
// One kernel, 6 device-wide barriers. 1024 blocks x 256 thr, 4 blocks/CU.
// amdgpu_waves_per_eu(4,4): min=max pins the allocator at exactly 4 waves/EU ->
// VGPR budget 128, and (critically) NO incentive to spill down to 64/48 to chase
// higher occupancy (r8/r9: launch_bounds min-only let the backend over-target
// occupancy and voluntarily spill; r9's +1GB scratch traffic was the smoking gun).
__global__ __attribute__((amdgpu_flat_work_group_size(256, 256), amdgpu_waves_per_eu(4, 4)))
void fusedK(
        const int* __restrict__ src, const int* __restrict__ dst,
        const int* __restrict__ rowptr, int* __restrict__ fill,
        const float* __restrict__ dis, uint2* __restrict__ erec, int E,
        const ushort_t* __restrict__ Wt2, const ushort_t* __restrict__ Wt3,
        ushort_t* __restrict__ tbuf, ushort_t* __restrict__ gbuf,
        const float* __restrict__ cvec, float* __restrict__ stats,
        void* __restrict__ outv, int n, const ushort_t* __restrict__ flagRef,
        int* __restrict__ blines, int* __restrict__ bmid, int* __restrict__ brel) {
    __shared__ char smem[17408];           // mm: 2x8KB A dbuf + 1KB scw | agg: 4KB red
    const int NB  = gridDim.x;
    const int tid = threadIdx.x;
    const int lane = tid & 63, wave = tid >> 6;

    const float* c_b1  = cvec;        const float* c_b2  = cvec + 128;
    const float* c_b3  = cvec + 256;  const float* c_g1  = cvec + 384;
    const float* c_g2  = cvec + 512;  const float* c_g3  = cvec + 640;
    const float* c_be1 = cvec + 768;  const float* c_be2 = cvec + 896;
    const float* c_be3 = cvec + 1024; const float* c_Wf  = cvec + 1152;
    const float* c_bf  = cvec + 1280;
    float* ssum0 = stats;            float* ssq0 = stats + 4096;
    float* ssum1 = stats + 8192;     float* ssq1 = stats + 12288;
    float* ssum2 = stats + 16384;    float* ssq2 = stats + 20480;

    // ---------------- P0: CSR scatter ----------------
    for (int e = blockIdx.x * 256 + tid; e < E; e += NB * 256) {
        int d = dst[e], s = src[e];
        int old = atomicSub(&fill[d], 1);
        int pos = rowptr[d] + old - 1;
        float c = dis[s] * dis[d];
        uint2 r; r.x = (unsigned)s; r.y = __builtin_bit_cast(unsigned, c);
        erec[pos] = r;
    }

    // ---------------- agg phase (t -> g, bias, stats) ----------------
    auto aggPhase = [&](const ushort_t* __restrict__ t, ushort_t* __restrict__ g,
                        const float* __restrict__ bias,
                        float* __restrict__ ssum, float* __restrict__ ssq) {
        const int grp = lane >> 4, p = lane & 15, cb = p * 8;
        float bch[8];
#pragma unroll
        for (int j = 0; j < 8; ++j) bch[j] = bias[cb + j];
        float s[8], q[8];
#pragma unroll
        for (int j = 0; j < 8; ++j) { s[j] = 0.f; q[j] = 0.f; }

        for (int node = blockIdx.x * 16 + wave * 4 + grp; node < n; node += NB * 16) {
            float d = dis[node];
            float d2 = d * d;
            float a[8];
#pragma unroll
            for (int j = 0; j < 8; ++j) a[j] = 0.f;
            uint4 sv = *(const uint4*)(t + (size_t)node * HH + cb);
            acc8(sv, d2, a);

            const int beg = rowptr[node], end = rowptr[node + 1];
            int e = beg;
            for (; e + 8 <= end; e += 8) {
                uint2 rr[8];
#pragma unroll
                for (int kk = 0; kk < 8; ++kk) rr[kk] = erec[e + kk];
                uint4 w0[4];
#pragma unroll
                for (int kk = 0; kk < 4; ++kk)
                    w0[kk] = *(const uint4*)(t + (size_t)rr[kk].x * HH + cb);
                uint4 w1[4];
#pragma unroll
                for (int kk = 0; kk < 4; ++kk)
                    w1[kk] = *(const uint4*)(t + (size_t)rr[4 + kk].x * HH + cb);
#pragma unroll
                for (int kk = 0; kk < 4; ++kk)
                    acc8(w0[kk], __builtin_bit_cast(float, rr[kk].y), a);
#pragma unroll
                for (int kk = 0; kk < 4; ++kk)
                    acc8(w1[kk], __builtin_bit_cast(float, rr[4 + kk].y), a);
            }
            if (e < end) {
                uint2 rr[8];
#pragma unroll
                for (int kk = 0; kk < 8; ++kk) {
                    int idx = e + kk;
                    rr[kk] = (idx < end) ? erec[idx] : (uint2){0u, 0u};
                }
                uint4 w0[4];
#pragma unroll
                for (int kk = 0; kk < 4; ++kk)
                    w0[kk] = *(const uint4*)(t + (size_t)rr[kk].x * HH + cb);
                uint4 w1[4];
#pragma unroll
                for (int kk = 0; kk < 4; ++kk)
                    w1[kk] = *(const uint4*)(t + (size_t)rr[4 + kk].x * HH + cb);
#pragma unroll
                for (int kk = 0; kk < 4; ++kk)
                    acc8(w0[kk], __builtin_bit_cast(float, rr[kk].y), a);
#pragma unroll
                for (int kk = 0; kk < 4; ++kk)
                    acc8(w1[kk], __builtin_bit_cast(float, rr[4 + kk].y), a);
            }

            ushort8 pk;
#pragma unroll
            for (int j = 0; j < 8; ++j) {
                a[j] += bch[j];
                pk[j] = f2bf(a[j]);
                s[j] += a[j]; q[j] += a[j] * a[j];
            }
            *(ushort8*)(g + (size_t)node * HH + cb) = pk;
        }

#pragma unroll
        for (int j = 0; j < 8; ++j) {
            s[j] += __shfl_xor(s[j], 16); s[j] += __shfl_xor(s[j], 32);
            q[j] += __shfl_xor(q[j], 16); q[j] += __shfl_xor(q[j], 32);
        }
        float (*red)[16][16] = (float (*)[16][16])smem;
        __syncthreads();                       // smem free from prior phase
        if (grp == 0) {
#pragma unroll
            for (int j = 0; j < 8; ++j) { red[wave][p][j] = s[j]; red[wave][p][8 + j] = q[j]; }
        }
        __syncthreads();
        {
            int ch = tid & 127, kind = tid >> 7;
            float S = 0.f;
#pragma unroll
            for (int w = 0; w < 4; ++w) S += red[w][ch >> 3][kind * 8 + (ch & 7)];
            int slice = (blockIdx.x & (STAT_SLICES - 1)) * HH;
            atomicAdd((kind ? ssq : ssum) + slice + ch, S);
        }
    };

    // ---------------- mm+BN phase (A -> out, K=128, W in regs) ----------------
    auto mmPhase = [&](const ushort_t* __restrict__ A, const ushort_t* __restrict__ Wt,
                       ushort_t* __restrict__ out,
                       const float* __restrict__ ssum, const float* __restrict__ ssq,
                       const float* __restrict__ gam, const float* __restrict__ bet) {
        float* scw = (float*)(smem + 16384);
        if (tid < 128) {
            float S = 0.f, Q = 0.f;
#pragma unroll
            for (int sl = 0; sl < STAT_SLICES; ++sl) { S += ssum[sl * HH + tid]; Q += ssq[sl * HH + tid]; }
            float invn = 1.0f / (float)n;
            float mu = S * invn;
            float var = fmaxf(Q * invn - mu * mu, 0.f);
            float sc = gam[tid] * rsqrtf(var + EPS);
            scw[tid] = sc;
            scw[128 + tid] = bet[tid] - mu * sc;
        }
        const int m = lane & 15, q4 = lane >> 4;
        ushort8 wfrag[4][2];
#pragma unroll
        for (int s = 0; s < 4; ++s)
#pragma unroll
            for (int tt = 0; tt < 2; ++tt)
                wfrag[s][tt] = *(const ushort8*)&Wt[(size_t)((wave * 2 + tt) * 16 + m) * 128 + s * 32 + q4 * 8];

        const int sr = tid >> 3, sa = tid & 7;   // stage: row sr (0..31), 32B block sa
        char* b0 = smem;
        char* b1 = smem + 8192;
        ushort8 sv[2];

        auto sLoad = [&](int T) {
            int row = T * 32 + sr; if (row >= n) row = n - 1;
            const ushort_t* ap = A + (size_t)row * HH + sa * 16;
            sv[0] = *(const ushort8*)ap;
            sv[1] = *(const ushort8*)(ap + 8);
        };
        auto sWrite = [&](char* buf) {
#pragma unroll
            for (int j = 0; j < 2; ++j) {
                int u = (sa * 2 + j) ^ (sr & 7);
                *(ushort8*)(buf + sr * 256 + u * 16) = sv[j];
            }
        };
        auto comp = [&](int T, const char* buf) {
            f32x4 acc[2][2];
#pragma unroll
            for (int bb = 0; bb < 2; ++bb)
#pragma unroll
                for (int tt = 0; tt < 2; ++tt) acc[bb][tt] = (f32x4){0.f, 0.f, 0.f, 0.f};
#pragma unroll
            for (int bb = 0; bb < 2; ++bb) {
                const char* arow = buf + (bb * 16 + m) * 256;
#pragma unroll
                for (int s = 0; s < 4; ++s) {
                    ushort8 av = *(const ushort8*)(arow + (((s * 4 + q4) ^ (m & 7)) * 16));
                    int kb = s * 32 + q4 * 8;
#pragma unroll
                    for (int j = 0; j < 8; ++j)
                        av[j] = f2bf(fmaxf(bf2f(av[j]) * scw[kb + j] + scw[128 + kb + j], 0.f));
                    bf16x8 nf = __builtin_bit_cast(bf16x8, av);
#pragma unroll
                    for (int tt = 0; tt < 2; ++tt)
                        acc[bb][tt] = __builtin_amdgcn_mfma_f32_16x16x32_bf16(
                            __builtin_bit_cast(bf16x8, wfrag[s][tt]), nf, acc[bb][tt], 0, 0, 0);
                }
            }
#pragma unroll
            for (int bb = 0; bb < 2; ++bb) {
                int node = T * 32 + bb * 16 + m;
                if (node < n) {
#pragma unroll
                    for (int tt = 0; tt < 2; ++tt) {
                        ushort4v pk;
#pragma unroll
                        for (int r = 0; r < 4; ++r) pk[r] = f2bf(acc[bb][tt][r]);
                        *(ushort4v*)(out + (size_t)node * HH + (wave * 2 + tt) * 16 + q4 * 4) = pk;
                    }
                }
            }
        };

        const int nT = (n + 31) >> 5;
        int T = blockIdx.x, pp = 0;
        if (T < nT) sLoad(T);
        __syncthreads();                       // scw ready; smem free from prior phase
        if (T < nT) sWrite(b0);
        __syncthreads();
        while (T < nT) {
            int Tn = T + NB;
            if (Tn < nT) sLoad(Tn);
            comp(T, pp ? b1 : b0);
            if (Tn >= nT) break;
            sWrite(pp ? b0 : b1);
            __syncthreads();
            T = Tn; pp ^= 1;
        }
    };

    // ---------------- phase chain ----------------
    gridSync(blines, bmid, brel, 1, NB);
    aggPhase(tbuf, gbuf, c_b1, ssum0, ssq0);
    gridSync(blines, bmid, brel, 2, NB);
    mmPhase(gbuf, Wt2, tbuf, ssum0, ssq0, c_g1, c_be1);
    gridSync(blines, bmid, brel, 3, NB);
    aggPhase(tbuf, gbuf, c_b2, ssum1, ssq1);
    gridSync(blines, bmid, brel, 4, NB);
    mmPhase(gbuf, Wt3, tbuf, ssum1, ssq1, c_g2, c_be2);
    gridSync(blines, bmid, brel, 5, NB);
    aggPhase(tbuf, gbuf, c_b3, ssum2, ssq2);
    gridSync(blines, bmid, brel, 6, NB);

    // ---------------- P6: output head ----------------
    {
        float* scw = (float*)(smem + 16384);
        if (tid < 128) {
            float S = 0.f, Q = 0.f;
#pragma unroll
            for (int sl = 0; sl < STAT_SLICES; ++sl) { S += ssum2[sl * HH + tid]; Q += ssq2[sl * HH + tid]; }
            float invn = 1.0f / (float)n;
            float mu = S * invn;
            float var = fmaxf(Q * invn - mu * mu, 0.f);
            float sc = c_g3[tid] * rsqrtf(var + EPS);
            scw[tid] = sc;
            scw[128 + tid] = c_be3[tid] - mu * sc;
        }
        __syncthreads();

        const int grp = lane >> 4, p = lane & 15, cb = p * 8;
        float w8[8], sc8[8], sh8[8];
#pragma unroll
        for (int j = 0; j < 8; ++j) {
            w8[j] = c_Wf[cb + j]; sc8[j] = scw[cb + j]; sh8[j] = scw[128 + cb + j];
        }
        const float bb = c_bf[0];
        const int flag = (flagRef[0] == 0x3F80) ? 1 : 0;

        for (int node = blockIdx.x * 16 + wave * 4 + grp; node < n; node += NB * 16) {
            uint4 v = *(const uint4*)(gbuf + (size_t)node * HH + cb);
            unsigned u[4] = {v.x, v.y, v.z, v.w};
            float x = 0.f;
#pragma unroll
            for (int j = 0; j < 4; ++j) {
                float f0 = __builtin_bit_cast(float, u[j] << 16);
                float f1 = __builtin_bit_cast(float, u[j] & 0xffff0000u);
                x += fmaxf(f0 * sc8[2 * j] + sh8[2 * j], 0.f) * w8[2 * j];
                x += fmaxf(f1 * sc8[2 * j + 1] + sh8[2 * j + 1], 0.f) * w8[2 * j + 1];
            }
#pragma unroll
            for (int off = 8; off; off >>= 1) x += __shfl_xor(x, off);
            if (p == 0) {
                float r = x + bb;
                if (flag) ((ushort_t*)outv)[node] = f2bf(r);
                else      ((float*)outv)[node] = r;
            }
        }
    }
}

// ================= launch =================
extern "C" void kernel_launch(void* const* d_in, const int* in_sizes, int n_in,
                              void* d_out, int out_size, void* d_ws, size_t ws_size,
                              hipStream_t stream) {
    const int DIN = 256;
    const int N = in_sizes[0] / DIN;
    const int E = in_sizes[1];

    const void* x   = d_in[0];
    const int*  src = (const int*)d_in[1];
    const int*  dst = (const int*)d_in[2];
    const void* W1  = d_in[3];
    const void* b1  = d_in[4];
    const void* g1  = d_in[5];
    const void* be1 = d_in[6];
    const void* W2  = d_in[7];
    const void* b2  = d_in[8];
    const void* g2  = d_in[9];
    const void* be2 = d_in[10];
    const void* W3  = d_in[11];
    const void* b3  = d_in[12];
    const void* g3  = d_in[13];
    const void* be3 = d_in[14];
    const void* Wf  = d_in[15];
    const void* bfp = d_in[16];
    const ushort_t* flagRef = (const ushort_t*)g1;

    char* base = (char*)d_ws;
    size_t off = 0;
    auto carve = [&](size_t bytes) -> void* {
        void* p = base + off;
        off += (bytes + 255) & ~(size_t)255;
        return p;
    };
    int*      counts = (int*)carve((size_t)N * 4);
    float*    stats  = (float*)carve((size_t)3 * 2 * STAT_SLICES * HH * 4);
    int*      bar    = (int*)carve((size_t)(BAR_LINES * 64 + 64 + 8 * 64) * 4); // lines | mid | rel[8]
    size_t    zbytes = off;                       // memset range [0, zbytes)
    float*    dis    = (float*)carve((size_t)N * 4);
    int*      rowptr = (int*)carve((size_t)(N + 1) * 4);
    int*      partial= (int*)carve(256 * 4);
    uint2*    erec   = (uint2*)carve((size_t)E * 8);
    ushort_t* Wt1    = (ushort_t*)carve((size_t)128 * 256 * 2);
    ushort_t* Wt2    = (ushort_t*)carve((size_t)128 * 128 * 2);
    ushort_t* Wt3    = (ushort_t*)carve((size_t)128 * 128 * 2);
    ushort_t* tbuf   = (ushort_t*)carve((size_t)N * HH * 2);
    ushort_t* gbuf   = (ushort_t*)carve((size_t)N * HH * 2);
    float*    cvec   = (float*)carve((size_t)1281 * 4);

    const int nbScan = (N + 2047) / 2048;
    const int histB  = (E + 255) / 256;
    const int disB   = (N + 255) / 256;
    const int mm1B   = 1024;

    hipMemsetAsync(d_ws, 0, zbytes, stream);   // counts + stats + barrier

    preK<<<histB + 256 + 1, 256, 0, stream>>>(dst, counts, E, W1, Wt1, W2, Wt2, W3, Wt3,
                                              g1, b1, b2, b3, g2, g3, be1, be2, be3, Wf, bfp,
                                              cvec, histB);
    scanAdisK<<<nbScan + disB, 256, 0, stream>>>(counts, partial, dis, N, nbScan);
    mm1scanCK<<<nbScan + mm1B, 256, 0, stream>>>(x, Wt1, tbuf, N, flagRef,
                                                 counts, partial, rowptr, nbScan);
    fusedK<<<FB, 256, 0, stream>>>(src, dst, rowptr, counts, dis, erec, E,
                                   Wt2, Wt3, tbuf, gbuf, cvec, stats,
                                   d_out, N, flagRef,
                                   bar, bar + BAR_LINES * 64, bar + BAR_LINES * 64 + 64);
}

// Round 11
// 422.199 us; speedup vs baseline: 2.6821x; 1.9278x over previous
//
#include <hip/hip_runtime.h>
#include <hip/hip_bf16.h>

typedef unsigned short ushort_t;
typedef __bf16 bf16x8 __attribute__((ext_vector_type(8)));
typedef unsigned short ushort8 __attribute__((ext_vector_type(8)));
typedef unsigned short ushort4v __attribute__((ext_vector_type(4)));
typedef float f32x4 __attribute__((ext_vector_type(4)));

#define HH 128          // hidden dim
#define EPS 1e-5f
#define STAT_SLICES 32
#define MTILE 32        // mm1 tile rows
#define GAS __attribute__((address_space(1)))
#define LAS __attribute__((address_space(3)))

__device__ __forceinline__ float bf2f(ushort_t u) {
    unsigned v = ((unsigned)u) << 16;
    return __builtin_bit_cast(float, v);
}
__device__ __forceinline__ ushort_t f2bf(float f) {
    unsigned u = __builtin_bit_cast(unsigned, f);
    unsigned r = (u + 0x7fffu + ((u >> 16) & 1u)) >> 16;
    return (ushort_t)r;
}
__device__ __forceinline__ float cvt(const void* p, int i, int flag) {
    return flag ? bf2f(((const ushort_t*)p)[i]) : ((const float*)p)[i];
}
// async global->LDS DMA, 16B per lane; l must be wave-uniform (HW: base + lane*16)
__device__ __forceinline__ void dma16(const void* g, void* l) {
    __builtin_amdgcn_global_load_lds((const GAS unsigned*)g, (LAS unsigned*)l, 16, 0, 0);
}
// accumulate 8 bf16 channels (one uint4) scaled by c into a[8]
__device__ __forceinline__ void acc8(const uint4 w, float c, float a[8]) {
    unsigned x0 = w.x, x1 = w.y, x2 = w.z, x3 = w.w;
    a[0] = fmaf(__builtin_bit_cast(float, x0 << 16), c, a[0]);
    a[1] = fmaf(__builtin_bit_cast(float, x0 & 0xffff0000u), c, a[1]);
    a[2] = fmaf(__builtin_bit_cast(float, x1 << 16), c, a[2]);
    a[3] = fmaf(__builtin_bit_cast(float, x1 & 0xffff0000u), c, a[3]);
    a[4] = fmaf(__builtin_bit_cast(float, x2 << 16), c, a[4]);
    a[5] = fmaf(__builtin_bit_cast(float, x2 & 0xffff0000u), c, a[5]);
    a[6] = fmaf(__builtin_bit_cast(float, x3 << 16), c, a[6]);
    a[7] = fmaf(__builtin_bit_cast(float, x3 & 0xffff0000u), c, a[7]);
}

// ================= fused pre-kernel: hist | weight-transpose | setup =================
// Wt stored UNPADDED row-major: Wt1[128][256], Wt2/3[128][128]
__global__ void preK(const int* __restrict__ dst, int* __restrict__ counts, int E,
                     const void* W1, ushort_t* Wt1, const void* W2, ushort_t* Wt2,
                     const void* W3, ushort_t* Wt3,
                     const void* g1, const void* b1, const void* b2, const void* b3,
                     const void* g2, const void* g3, const void* be1, const void* be2,
                     const void* be3, const void* Wfp, const void* bfp,
                     float* __restrict__ cvec, int histB) {
    const int bid = blockIdx.x;
    const int tid = threadIdx.x;
    const int flag = (((const ushort_t*)g1)[0] == 0x3F80) ? 1 : 0;
    if (bid < histB) {
        int e = bid * 256 + tid;
        if (e < E) atomicAdd(&counts[dst[e]], 1);
    } else if (bid < histB + 256) {
        int idx = (bid - histB) * 256 + tid;   // 0..65535
        const void* W; ushort_t* Wt; int K;
        if (idx < 32768)      { W = W1; Wt = Wt1; K = 256; }
        else if (idx < 49152) { W = W2; Wt = Wt2; K = 128; idx -= 32768; }
        else                  { W = W3; Wt = Wt3; K = 128; idx -= 49152; }
        int k = idx >> 7, nn = idx & 127;
        Wt[nn * K + k] = flag ? ((const ushort_t*)W)[idx] : f2bf(((const float*)W)[idx]);
    } else {
        int t = tid;
        if (t < 128) {
            cvec[t]        = cvt(b1, t, flag);
            cvec[128 + t]  = cvt(b2, t, flag);
            cvec[256 + t]  = cvt(b3, t, flag);
            cvec[384 + t]  = cvt(g1, t, flag);
            cvec[512 + t]  = cvt(g2, t, flag);
            cvec[640 + t]  = cvt(g3, t, flag);
            cvec[768 + t]  = cvt(be1, t, flag);
            cvec[896 + t]  = cvt(be2, t, flag);
            cvec[1024 + t] = cvt(be3, t, flag);
            cvec[1152 + t] = cvt(Wfp, t, flag);
            if (t == 0) cvec[1280] = cvt(bfp, 0, flag);
        }
    }
}

// ================= fused: scanA (block sums) | disK =================
__global__ void scanAdisK(const int* __restrict__ cnt, int* __restrict__ partial,
                          float* __restrict__ dis, int n, int nbScan) {
    __shared__ int lds[256];
    const int tid = threadIdx.x;
    if ((int)blockIdx.x < nbScan) {
        int base = blockIdx.x * 2048 + tid * 8;
        int s = 0;
#pragma unroll
        for (int j = 0; j < 8; ++j) { int idx = base + j; if (idx < n) s += cnt[idx]; }
        lds[tid] = s; __syncthreads();
        for (int off = 128; off; off >>= 1) { if (tid < off) lds[tid] += lds[tid + off]; __syncthreads(); }
        if (tid == 0) partial[blockIdx.x] = lds[0];
    } else {
        int i = (blockIdx.x - nbScan) * 256 + tid;
        if (i < n) dis[i] = rsqrtf((float)cnt[i] + 1.0f);
    }
}

// scanC with local recompute of the partial prefix
__device__ __forceinline__ void scanC2Dev(int* lds, const int* __restrict__ cnt,
                                          const int* __restrict__ partial,
                                          int* __restrict__ rowptr, int n, int bid, int nb) {
    const int tid = threadIdx.x;
    int pre = 0, tot = 0;
    for (int i = 0; i < nb; ++i) { int v = partial[i]; if (i < bid) pre += v; tot += v; }
    int base = bid * 2048 + tid * 8;
    int v[8]; int s = 0;
#pragma unroll
    for (int j = 0; j < 8; ++j) { int idx = base + j; v[j] = (idx < n) ? cnt[idx] : 0; s += v[j]; }
    lds[tid] = s; __syncthreads();
    for (int off = 1; off < 256; off <<= 1) {
        int x = (tid >= off) ? lds[tid - off] : 0;
        __syncthreads();
        lds[tid] += x;
        __syncthreads();
    }
    int excl = lds[tid] - s;
    int off0 = pre + excl;
#pragma unroll
    for (int j = 0; j < 8; ++j) {
        int idx = base + j;
        if (idx < n) { rowptr[idx] = off0; off0 += v[j]; }
    }
    if (bid == 0 && tid == 0) rowptr[n] = tot;
}

// ================= CSR scatter: 8B records, slot via atomicSub on histogram ============
__global__ void scatterK(const int* __restrict__ src, const int* __restrict__ dst,
                         const int* __restrict__ rowptr, int* __restrict__ fill,
                         const float* __restrict__ dis,
                         uint2* __restrict__ erec, int E) {
    int e = blockIdx.x * 256 + threadIdx.x;
    if (e >= E) return;
    int d = dst[e], s = src[e];
    int old = atomicSub(&fill[d], 1);
    int pos = rowptr[d] + old - 1;
    float c = dis[s] * dis[d];
    uint2 r; r.x = (unsigned)s; r.y = __builtin_bit_cast(unsigned, c);
    erec[pos] = r;
}

// ================= mm layer1 (K=256): W in REGISTERS, cooperative bf16 A staging ======
__global__ __launch_bounds__(256) void mm1scanCK(const void* __restrict__ x,
                                                 const ushort_t* __restrict__ Wt1,
                                                 ushort_t* __restrict__ tbuf, int n,
                                                 const ushort_t* __restrict__ flagRef,
                                                 const int* __restrict__ cnt,
                                                 const int* __restrict__ partial,
                                                 int* __restrict__ rowptr, int nbScan) {
    __shared__ char smem[33792];           // 2 x 16KB A bufs | scanC scratch (1KB)
    const int tid = threadIdx.x;
    if ((int)blockIdx.x < nbScan) {
        scanC2Dev((int*)smem, cnt, partial, rowptr, n, blockIdx.x, nbScan);
        return;
    }
    const int arm = blockIdx.x - nbScan;
    const int NB  = gridDim.x - nbScan;
    const int nTiles = (n + MTILE - 1) / MTILE;
    if (arm >= nTiles) return;

    const int lane = tid & 63, wave = tid >> 6;
    const int m = lane & 15, q = lane >> 4;
    const int flag = (flagRef[0] == 0x3F80) ? 1 : 0;

    // ---- W fragments in registers: wave w covers out-ch groups t = 2w, 2w+1
    ushort8 wfrag[8][2];
#pragma unroll
    for (int s = 0; s < 8; ++s)
#pragma unroll
        for (int tt = 0; tt < 2; ++tt)
            wfrag[s][tt] = *(const ushort8*)&Wt1[(size_t)((wave * 2 + tt) * 16 + m) * 256 + s * 32 + q * 8];

    // staging thread mapping: row sr (0..31), 32 cols starting at sa*32
    const int sr = tid >> 3, sa = tid & 7;
    char* buf0 = smem;
    char* buf1 = smem + 16384;

    float4  f[8];
    ushort8 v[4];

    auto stageLoad = [&](int T) {
        int row = T * MTILE + sr; if (row >= n) row = n - 1;
        if (flag) {
            const ushort_t* xp = (const ushort_t*)x + (size_t)row * 256 + sa * 32;
#pragma unroll
            for (int j = 0; j < 4; ++j) v[j] = *(const ushort8*)(xp + j * 8);
        } else {
            const float* xp = (const float*)x + (size_t)row * 256 + sa * 32;
#pragma unroll
            for (int j = 0; j < 8; ++j) f[j] = *(const float4*)(xp + j * 4);
        }
    };
    auto convWrite = [&](char* buf) {
        if (!flag) {
#pragma unroll
            for (int j = 0; j < 4; ++j) {
                float4 a = f[2 * j], b = f[2 * j + 1];
                ushort8 t8;
                t8[0] = f2bf(a.x); t8[1] = f2bf(a.y); t8[2] = f2bf(a.z); t8[3] = f2bf(a.w);
                t8[4] = f2bf(b.x); t8[5] = f2bf(b.y); t8[6] = f2bf(b.z); t8[7] = f2bf(b.w);
                v[j] = t8;
            }
        }
#pragma unroll
        for (int j = 0; j < 4; ++j) {
            int u = (sa * 4 + j) ^ (sr & 7);
            *(ushort8*)(buf + sr * 512 + u * 16) = v[j];
        }
    };
    auto computeStore = [&](int T, const char* buf) {
        f32x4 acc[2][2];
#pragma unroll
        for (int bb = 0; bb < 2; ++bb)
#pragma unroll
            for (int tt = 0; tt < 2; ++tt) acc[bb][tt] = (f32x4){0.f, 0.f, 0.f, 0.f};
#pragma unroll
        for (int bb = 0; bb < 2; ++bb) {
            const char* base = buf + (bb * 16 + m) * 512;
#pragma unroll
            for (int s = 0; s < 8; ++s) {
                ushort8 xf = *(const ushort8*)(base + (((s * 4 + q) ^ (m & 7)) * 16));
                bf16x8 xb = __builtin_bit_cast(bf16x8, xf);
#pragma unroll
                for (int tt = 0; tt < 2; ++tt)
                    acc[bb][tt] = __builtin_amdgcn_mfma_f32_16x16x32_bf16(
                        __builtin_bit_cast(bf16x8, wfrag[s][tt]), xb, acc[bb][tt], 0, 0, 0);
            }
        }
#pragma unroll
        for (int bb = 0; bb < 2; ++bb) {
            int node = T * MTILE + bb * 16 + m;
            if (node < n) {
#pragma unroll
                for (int tt = 0; tt < 2; ++tt) {
                    ushort4v pk;
#pragma unroll
                    for (int r = 0; r < 4; ++r) pk[r] = f2bf(acc[bb][tt][r]);
                    *(ushort4v*)(tbuf + (size_t)node * HH + (wave * 2 + tt) * 16 + q * 4) = pk;
                }
            }
        }
    };

    // prologue
    stageLoad(arm); convWrite(buf0);
    __syncthreads();
    int T = arm, pp = 0;
    while (true) {
        int Tn = T + NB;
        bool more = (Tn < nTiles);
        if (more) stageLoad(Tn);               // issue next-tile loads early
        computeStore(T, pp ? buf1 : buf0);     // hide load latency under MFMAs
        if (!more) break;
        convWrite(pp ? buf0 : buf1);
        __syncthreads();
        T = Tn; pp ^= 1;
    }
}

// ================= mmBN (K=128, full 128ch): W 32KB + A 16KB + scw -> 3 blocks/CU ======
__global__ __launch_bounds__(256) void mmBNK(const ushort_t* __restrict__ A,
                                             const ushort_t* __restrict__ Wt,
                                             ushort_t* __restrict__ out, int n,
                                             const float* __restrict__ ssum,
                                             const float* __restrict__ ssq,
                                             const float* __restrict__ gam,
                                             const float* __restrict__ bet) {
    __shared__ char smem[50176];           // W 32768 | A 16384 | scw 1024
    char* abuf = smem + 32768;
    float* scw = (float*)(smem + 49152);
    const int tid = threadIdx.x;

    if (tid < 128) {
        float S = 0.f, Q = 0.f;
#pragma unroll
        for (int sl = 0; sl < STAT_SLICES; ++sl) { S += ssum[sl * HH + tid]; Q += ssq[sl * HH + tid]; }
        float invn = 1.0f / (float)n;
        float mu = S * invn;
        float var = fmaxf(Q * invn - mu * mu, 0.f);
        float sc = gam[tid] * rsqrtf(var + EPS);
        scw[tid] = sc;
        scw[128 + tid] = bet[tid] - mu * sc;
    }
#pragma unroll
    for (int it = 0; it < 8; ++it) {
        int idx = tid + it * 256;          // 0..2047 = 128 rows x 16 segs
        int r = idx >> 4, seg = idx & 15;
        int p = seg ^ (r & 7);
        *(uint4*)&smem[r * 256 + p * 16] = *(const uint4*)&Wt[(size_t)r * 128 + seg * 8];
    }
    __syncthreads();

    const int lane = tid & 63, wave = tid >> 6;
    const int m = lane & 15, q = lane >> 4;
    const int nTiles = (n + 63) >> 6;

    for (int tile = blockIdx.x; tile < nTiles; tile += gridDim.x) {
        const int row0 = tile * 64 + wave * 16;
        // 4 DMA instrs: rows row0+4j .. +4 (1KB each, 256B rows)
#pragma unroll
        for (int j = 0; j < 4; ++j) {
            int r = row0 + j * 4;
            if (r + 3 >= n) r = n - 4;
            const char* g = (const char*)A + (size_t)r * 256 + lane * 16;
            dma16(g, abuf + (wave * 16 + j * 4) * 256);
        }
        __builtin_amdgcn_s_waitcnt(0x0F70);   // vmcnt(0)

        f32x4 acc[8];
#pragma unroll
        for (int t = 0; t < 8; ++t) acc[t] = (f32x4){0.f, 0.f, 0.f, 0.f};
        const char* arow = abuf + (wave * 16 + m) * 256;
#pragma unroll
        for (int s = 0; s < 4; ++s) {
            ushort8 av = *(const ushort8*)(arow + s * 64 + q * 16);
            int kb = s * 32 + q * 8;
#pragma unroll
            for (int j = 0; j < 8; ++j)
                av[j] = f2bf(fmaxf(bf2f(av[j]) * scw[kb + j] + scw[128 + kb + j], 0.f));
            bf16x8 nf = __builtin_bit_cast(bf16x8, av);
#pragma unroll
            for (int t = 0; t < 8; ++t) {
                int p = (s * 4 + q) ^ (m & 7);
                ushort8 wv = *(const ushort8*)&smem[(t * 16 + m) * 256 + p * 16];
                acc[t] = __builtin_amdgcn_mfma_f32_16x16x32_bf16(
                    __builtin_bit_cast(bf16x8, wv), nf, acc[t], 0, 0, 0);
            }
        }
        int node = tile * 64 + wave * 16 + m;
        if (node < n) {
            ushort_t* op = out + (size_t)node * HH + q * 4;
#pragma unroll
            for (int t = 0; t < 8; ++t) {
                ushort4v pk;
#pragma unroll
                for (int r = 0; r < 4; ++r) pk[r] = f2bf(acc[t][r]);
                *(ushort4v*)(op + t * 16) = pk;
            }
        }
    }
}

// ================= aggregation + bias + fused BN stats ==================================
// 4 nodes/wave (16 lanes/node, 8 ch/lane). Direct broadcast erec reads (same addr
// across the 16-lane group -> HW broadcast, no shfl chain) + 8 edge-rows in flight
// (two clusters of 4) + unguarded fast path for full 8-edge batches (avg degree = 8).
__global__ __launch_bounds__(256) void aggK(const ushort_t* __restrict__ t,
                                            const uint2* __restrict__ erec,
                                            const int* __restrict__ rowptr,
                                            const float* __restrict__ dis,
                                            const float* __restrict__ bias,
                                            ushort_t* __restrict__ g,
                                            float* __restrict__ ssum, float* __restrict__ ssq,
                                            int n) {
    const int tid  = threadIdx.x;
    const int lane = tid & 63;
    const int wave = tid >> 6;
    const int grp  = lane >> 4;            // 0..3: node slot within wave
    const int p    = lane & 15;            // channel slot: channels p*8 .. p*8+7
    const int cb   = p * 8;

    float bch[8];
#pragma unroll
    for (int j = 0; j < 8; ++j) bch[j] = bias[cb + j];

    float s[8], q[8];
#pragma unroll
    for (int j = 0; j < 8; ++j) { s[j] = 0.f; q[j] = 0.f; }

    for (int node = blockIdx.x * 16 + wave * 4 + grp; node < n; node += gridDim.x * 16) {
        float d = dis[node];
        float d2 = d * d;
        float a[8];
#pragma unroll
        for (int j = 0; j < 8; ++j) a[j] = 0.f;
        // self-loop term
        uint4 sv = *(const uint4*)(t + (size_t)node * HH + cb);
        acc8(sv, d2, a);

        const int beg = rowptr[node], end = rowptr[node + 1];
        int e = beg;
        // fast path: full 8-edge batches, no predication
        for (; e + 8 <= end; e += 8) {
            uint2 rr[8];
#pragma unroll
            for (int kk = 0; kk < 8; ++kk) rr[kk] = erec[e + kk];   // group-broadcast
            uint4 w0[4];
#pragma unroll
            for (int kk = 0; kk < 4; ++kk)
                w0[kk] = *(const uint4*)(t + (size_t)rr[kk].x * HH + cb);
            uint4 w1[4];
#pragma unroll
            for (int kk = 0; kk < 4; ++kk)
                w1[kk] = *(const uint4*)(t + (size_t)rr[4 + kk].x * HH + cb);
#pragma unroll
            for (int kk = 0; kk < 4; ++kk)
                acc8(w0[kk], __builtin_bit_cast(float, rr[kk].y), a);
#pragma unroll
            for (int kk = 0; kk < 4; ++kk)
                acc8(w1[kk], __builtin_bit_cast(float, rr[4 + kk].y), a);
        }
        // guarded tail (up to 7 edges); invalid slots read row 0 with coef 0
        if (e < end) {
            uint2 rr[8];
#pragma unroll
            for (int kk = 0; kk < 8; ++kk) {
                int idx = e + kk;
                rr[kk] = (idx < end) ? erec[idx] : (uint2){0u, 0u};
            }
            uint4 w0[4];
#pragma unroll
            for (int kk = 0; kk < 4; ++kk)
                w0[kk] = *(const uint4*)(t + (size_t)rr[kk].x * HH + cb);
            uint4 w1[4];
#pragma unroll
            for (int kk = 0; kk < 4; ++kk)
                w1[kk] = *(const uint4*)(t + (size_t)rr[4 + kk].x * HH + cb);
#pragma unroll
            for (int kk = 0; kk < 4; ++kk)
                acc8(w0[kk], __builtin_bit_cast(float, rr[kk].y), a);
#pragma unroll
            for (int kk = 0; kk < 4; ++kk)
                acc8(w1[kk], __builtin_bit_cast(float, rr[4 + kk].y), a);
        }

        ushort8 pk;
#pragma unroll
        for (int j = 0; j < 8; ++j) {
            a[j] += bch[j];
            pk[j] = f2bf(a[j]);
            s[j] += a[j]; q[j] += a[j] * a[j];
        }
        *(ushort8*)(g + (size_t)node * HH + cb) = pk;      // 16B/lane, 256B/group burst
    }

    // reduce across the 4 groups (lanes p, p+16, p+32, p+48 hold same channels)
#pragma unroll
    for (int j = 0; j < 8; ++j) {
        s[j] += __shfl_xor(s[j], 16); s[j] += __shfl_xor(s[j], 32);
        q[j] += __shfl_xor(q[j], 16); q[j] += __shfl_xor(q[j], 32);
    }
    __shared__ float red[4][16][16];
    if (grp == 0) {
#pragma unroll
        for (int j = 0; j < 8; ++j) { red[wave][p][j] = s[j]; red[wave][p][8 + j] = q[j]; }
    }
    __syncthreads();
    {
        int ch = tid & 127, kind = tid >> 7;               // 256 threads -> 256 atomics
        float S = 0.f;
#pragma unroll
        for (int w = 0; w < 4; ++w) S += red[w][ch >> 3][kind * 8 + (ch & 7)];
        int slice = (blockIdx.x & (STAT_SLICES - 1)) * HH;
        atomicAdd((kind ? ssq : ssum) + slice + ch, S);
    }
}

// ================= final head: inline stats finalize + relu(bn(g)) @ Wf + bf ===========
__global__ __launch_bounds__(256) void outK(const ushort_t* __restrict__ g,
                                            const float* __restrict__ ssum,
                                            const float* __restrict__ ssq,
                                            const float* __restrict__ gam,
                                            const float* __restrict__ bet,
                                            const float* __restrict__ Wf,
                                            const float* __restrict__ bfp,
                                            void* __restrict__ outv, int n,
                                            const ushort_t* __restrict__ flagRef) {
    __shared__ float scw[256];
    const int tid = threadIdx.x;
    if (tid < 128) {
        float S = 0.f, Q = 0.f;
#pragma unroll
        for (int sl = 0; sl < STAT_SLICES; ++sl) { S += ssum[sl * HH + tid]; Q += ssq[sl * HH + tid]; }
        float invn = 1.0f / (float)n;
        float mu = S * invn;
        float var = fmaxf(Q * invn - mu * mu, 0.f);
        float sc = gam[tid] * rsqrtf(var + EPS);
        scw[tid] = sc;
        scw[128 + tid] = bet[tid] - mu * sc;
    }
    __syncthreads();

    const int lane = tid & 63;
    const int wave = tid >> 6;
    const int grp  = lane >> 4;
    const int p    = lane & 15;
    const int cb   = p * 8;
    float w8[8], sc8[8], sh8[8];
#pragma unroll
    for (int j = 0; j < 8; ++j) {
        w8[j] = Wf[cb + j]; sc8[j] = scw[cb + j]; sh8[j] = scw[128 + cb + j];
    }
    const float bb = bfp[0];
    const int flag = (flagRef[0] == 0x3F80) ? 1 : 0;

    for (int node = blockIdx.x * 16 + wave * 4 + grp; node < n; node += gridDim.x * 16) {
        uint4 v = *(const uint4*)(g + (size_t)node * HH + cb);
        unsigned u[4] = {v.x, v.y, v.z, v.w};
        float x = 0.f;
#pragma unroll
        for (int j = 0; j < 4; ++j) {
            float f0 = __builtin_bit_cast(float, u[j] << 16);
            float f1 = __builtin_bit_cast(float, u[j] & 0xffff0000u);
            x += fmaxf(f0 * sc8[2 * j] + sh8[2 * j], 0.f) * w8[2 * j];
            x += fmaxf(f1 * sc8[2 * j + 1] + sh8[2 * j + 1], 0.f) * w8[2 * j + 1];
        }
#pragma unroll
        for (int off = 8; off; off >>= 1) x += __shfl_xor(x, off);   // within 16-lane group
        if (p == 0) {
            float r = x + bb;
            if (flag) ((ushort_t*)outv)[node] = f2bf(r);
            else      ((float*)outv)[node] = r;
        }
    }
}

// ================= launch =================
extern "C" void kernel_launch(void* const* d_in, const int* in_sizes, int n_in,
                              void* d_out, int out_size, void* d_ws, size_t ws_size,
                              hipStream_t stream) {
    const int DIN = 256;
    const int N = in_sizes[0] / DIN;
    const int E = in_sizes[1];

    const void* x   = d_in[0];
    const int*  src = (const int*)d_in[1];
    const int*  dst = (const int*)d_in[2];
    const void* W1  = d_in[3];
    const void* b1  = d_in[4];
    const void* g1  = d_in[5];
    const void* be1 = d_in[6];
    const void* W2  = d_in[7];
    const void* b2  = d_in[8];
    const void* g2  = d_in[9];
    const void* be2 = d_in[10];
    const void* W3  = d_in[11];
    const void* b3  = d_in[12];
    const void* g3  = d_in[13];
    const void* be3 = d_in[14];
    const void* Wf  = d_in[15];
    const void* bfp = d_in[16];
    const ushort_t* flagRef = (const ushort_t*)g1;

    char* base = (char*)d_ws;
    size_t off = 0;
    auto carve = [&](size_t bytes) -> void* {
        void* p = base + off;
        off += (bytes + 255) & ~(size_t)255;
        return p;
    };
    int*      counts = (int*)carve((size_t)N * 4);
    float*    stats  = (float*)carve((size_t)3 * 2 * STAT_SLICES * HH * 4);
    size_t    zbytes = off;                       // memset range [0, zbytes)
    float*    dis    = (float*)carve((size_t)N * 4);
    int*      rowptr = (int*)carve((size_t)(N + 1) * 4);
    int*      partial= (int*)carve(256 * 4);
    uint2*    erec   = (uint2*)carve((size_t)E * 8);
    ushort_t* Wt1    = (ushort_t*)carve((size_t)128 * 256 * 2);
    ushort_t* Wt2    = (ushort_t*)carve((size_t)128 * 128 * 2);
    ushort_t* Wt3    = (ushort_t*)carve((size_t)128 * 128 * 2);
    ushort_t* tbuf   = (ushort_t*)carve((size_t)N * HH * 2);
    ushort_t* gbuf   = (ushort_t*)carve((size_t)N * HH * 2);
    float*    cvec   = (float*)carve((size_t)1281 * 4);

    float* ssum0 = stats;                         float* ssq0 = ssum0 + STAT_SLICES * HH;
    float* ssum1 = ssq0 + STAT_SLICES * HH;       float* ssq1 = ssum1 + STAT_SLICES * HH;
    float* ssum2 = ssq1 + STAT_SLICES * HH;       float* ssq2 = ssum2 + STAT_SLICES * HH;

    float* c_b1 = cvec;         float* c_b2 = cvec + 128;  float* c_b3 = cvec + 256;
    float* c_g1 = cvec + 384;   float* c_g2 = cvec + 512;  float* c_g3 = cvec + 640;
    float* c_be1 = cvec + 768;  float* c_be2 = cvec + 896; float* c_be3 = cvec + 1024;
    float* c_Wf = cvec + 1152;  float* c_bf = cvec + 1280;

    const int nbScan = (N + 2047) / 2048;
    const int histB  = (E + 255) / 256;
    const int disB   = (N + 255) / 256;
    const int aggB   = 2048;
    const int mm1B   = 1024;

    hipMemsetAsync(d_ws, 0, zbytes, stream);   // counts + stats

    preK<<<histB + 256 + 1, 256, 0, stream>>>(dst, counts, E, W1, Wt1, W2, Wt2, W3, Wt3,
                                              g1, b1, b2, b3, g2, g3, be1, be2, be3, Wf, bfp,
                                              cvec, histB);
    scanAdisK<<<nbScan + disB, 256, 0, stream>>>(counts, partial, dis, N, nbScan);
    mm1scanCK<<<nbScan + mm1B, 256, 0, stream>>>(x, Wt1, tbuf, N, flagRef,
                                                 counts, partial, rowptr, nbScan);
    scatterK<<<histB, 256, 0, stream>>>(src, dst, rowptr, counts, dis, erec, E);

    aggK<<<aggB, 256, 0, stream>>>(tbuf, erec, rowptr, dis, c_b1, gbuf, ssum0, ssq0, N);
    mmBNK<<<768, 256, 0, stream>>>(gbuf, Wt2, tbuf, N, ssum0, ssq0, c_g1, c_be1);
    aggK<<<aggB, 256, 0, stream>>>(tbuf, erec, rowptr, dis, c_b2, gbuf, ssum1, ssq1, N);
    mmBNK<<<768, 256, 0, stream>>>(gbuf, Wt3, tbuf, N, ssum1, ssq1, c_g2, c_be2);
    aggK<<<aggB, 256, 0, stream>>>(tbuf, erec, rowptr, dis, c_b3, gbuf, ssum2, ssq2, N);
    outK<<<1024, 256, 0, stream>>>(gbuf, ssum2, ssq2, c_g3, c_be3, c_Wf, c_bf, d_out, N, flagRef);
}

// Round 12
// 420.554 us; speedup vs baseline: 2.6925x; 1.0039x over previous
//
#include <hip/hip_runtime.h>
#include <hip/hip_bf16.h>

typedef unsigned short ushort_t;
typedef __bf16 bf16x8 __attribute__((ext_vector_type(8)));
typedef unsigned short ushort8 __attribute__((ext_vector_type(8)));
typedef unsigned short ushort4v __attribute__((ext_vector_type(4)));
typedef float f32x4 __attribute__((ext_vector_type(4)));

#define HH 128          // hidden dim
#define EPS 1e-5f
#define STAT_SLICES 32
#define MTILE 32        // mm1 tile rows
#define GAS __attribute__((address_space(1)))
#define LAS __attribute__((address_space(3)))

__device__ __forceinline__ float bf2f(ushort_t u) {
    unsigned v = ((unsigned)u) << 16;
    return __builtin_bit_cast(float, v);
}
__device__ __forceinline__ ushort_t f2bf(float f) {
    unsigned u = __builtin_bit_cast(unsigned, f);
    unsigned r = (u + 0x7fffu + ((u >> 16) & 1u)) >> 16;
    return (ushort_t)r;
}
__device__ __forceinline__ float cvt(const void* p, int i, int flag) {
    return flag ? bf2f(((const ushort_t*)p)[i]) : ((const float*)p)[i];
}
// async global->LDS DMA, 16B per lane; l must be wave-uniform (HW: base + lane*16)
__device__ __forceinline__ void dma16(const void* g, void* l) {
    __builtin_amdgcn_global_load_lds((const GAS unsigned*)g, (LAS unsigned*)l, 16, 0, 0);
}
// accumulate 8 bf16 channels (one uint4) scaled by c into a[8]
__device__ __forceinline__ void acc8(const uint4 w, float c, float a[8]) {
    unsigned x0 = w.x, x1 = w.y, x2 = w.z, x3 = w.w;
    a[0] = fmaf(__builtin_bit_cast(float, x0 << 16), c, a[0]);
    a[1] = fmaf(__builtin_bit_cast(float, x0 & 0xffff0000u), c, a[1]);
    a[2] = fmaf(__builtin_bit_cast(float, x1 << 16), c, a[2]);
    a[3] = fmaf(__builtin_bit_cast(float, x1 & 0xffff0000u), c, a[3]);
    a[4] = fmaf(__builtin_bit_cast(float, x2 << 16), c, a[4]);
    a[5] = fmaf(__builtin_bit_cast(float, x2 & 0xffff0000u), c, a[5]);
    a[6] = fmaf(__builtin_bit_cast(float, x3 << 16), c, a[6]);
    a[7] = fmaf(__builtin_bit_cast(float, x3 & 0xffff0000u), c, a[7]);
}

// ================= fused pre-kernel: hist | weight-transpose | setup =================
// Wt stored UNPADDED row-major: Wt1[128][256], Wt2/3[128][128]
__global__ void preK(const int* __restrict__ dst, int* __restrict__ counts, int E,
                     const void* W1, ushort_t* Wt1, const void* W2, ushort_t* Wt2,
                     const void* W3, ushort_t* Wt3,
                     const void* g1, const void* b1, const void* b2, const void* b3,
                     const void* g2, const void* g3, const void* be1, const void* be2,
                     const void* be3, const void* Wfp, const void* bfp,
                     float* __restrict__ cvec, int histB) {
    const int bid = blockIdx.x;
    const int tid = threadIdx.x;
    const int flag = (((const ushort_t*)g1)[0] == 0x3F80) ? 1 : 0;
    if (bid < histB) {
        int e = bid * 256 + tid;
        if (e < E) atomicAdd(&counts[dst[e]], 1);
    } else if (bid < histB + 256) {
        int idx = (bid - histB) * 256 + tid;   // 0..65535
        const void* W; ushort_t* Wt; int K;
        if (idx < 32768)      { W = W1; Wt = Wt1; K = 256; }
        else if (idx < 49152) { W = W2; Wt = Wt2; K = 128; idx -= 32768; }
        else                  { W = W3; Wt = Wt3; K = 128; idx -= 49152; }
        int k = idx >> 7, nn = idx & 127;
        Wt[nn * K + k] = flag ? ((const ushort_t*)W)[idx] : f2bf(((const float*)W)[idx]);
    } else {
        int t = tid;
        if (t < 128) {
            cvec[t]        = cvt(b1, t, flag);
            cvec[128 + t]  = cvt(b2, t, flag);
            cvec[256 + t]  = cvt(b3, t, flag);
            cvec[384 + t]  = cvt(g1, t, flag);
            cvec[512 + t]  = cvt(g2, t, flag);
            cvec[640 + t]  = cvt(g3, t, flag);
            cvec[768 + t]  = cvt(be1, t, flag);
            cvec[896 + t]  = cvt(be2, t, flag);
            cvec[1024 + t] = cvt(be3, t, flag);
            cvec[1152 + t] = cvt(Wfp, t, flag);
            if (t == 0) cvec[1280] = cvt(bfp, 0, flag);
        }
    }
}

// ================= fused: scanA (block sums of PADDED counts) | disK =================
// rowptr is built on degrees padded to multiples of 8 (pad slots pre-zeroed erec ->
// src=0, coef=0: L1-hot no-op gathers). dis uses REAL counts.
__global__ void scanAdisK(const int* __restrict__ cnt, int* __restrict__ partial,
                          float* __restrict__ dis, int n, int nbScan) {
    __shared__ int lds[256];
    const int tid = threadIdx.x;
    if ((int)blockIdx.x < nbScan) {
        int base = blockIdx.x * 2048 + tid * 8;
        int s = 0;
#pragma unroll
        for (int j = 0; j < 8; ++j) {
            int idx = base + j;
            if (idx < n) s += (cnt[idx] + 7) & ~7;     // padded degree
        }
        lds[tid] = s; __syncthreads();
        for (int off = 128; off; off >>= 1) { if (tid < off) lds[tid] += lds[tid + off]; __syncthreads(); }
        if (tid == 0) partial[blockIdx.x] = lds[0];
    } else {
        int i = (blockIdx.x - nbScan) * 256 + tid;
        if (i < n) dis[i] = rsqrtf((float)cnt[i] + 1.0f);
    }
}

// scanC with local recompute of the partial prefix (PADDED degrees)
__device__ __forceinline__ void scanC2Dev(int* lds, const int* __restrict__ cnt,
                                          const int* __restrict__ partial,
                                          int* __restrict__ rowptr, int n, int bid, int nb) {
    const int tid = threadIdx.x;
    int pre = 0, tot = 0;
    for (int i = 0; i < nb; ++i) { int v = partial[i]; if (i < bid) pre += v; tot += v; }
    int base = bid * 2048 + tid * 8;
    int v[8]; int s = 0;
#pragma unroll
    for (int j = 0; j < 8; ++j) {
        int idx = base + j;
        v[j] = (idx < n) ? ((cnt[idx] + 7) & ~7) : 0;   // padded degree
        s += v[j];
    }
    lds[tid] = s; __syncthreads();
    for (int off = 1; off < 256; off <<= 1) {
        int x = (tid >= off) ? lds[tid - off] : 0;
        __syncthreads();
        lds[tid] += x;
        __syncthreads();
    }
    int excl = lds[tid] - s;
    int off0 = pre + excl;
#pragma unroll
    for (int j = 0; j < 8; ++j) {
        int idx = base + j;
        if (idx < n) { rowptr[idx] = off0; off0 += v[j]; }
    }
    if (bid == 0 && tid == 0) rowptr[n] = tot;
}

// ================= CSR scatter: 8B records, slot via atomicSub on histogram ============
// fill = REAL counts -> real edges land in [rowptr[d], rowptr[d]+realdeg); the pad
// slots [rowptr[d]+realdeg, rowptr[d]+paddeg) stay zero (erec is in the memset range).
__global__ void scatterK(const int* __restrict__ src, const int* __restrict__ dst,
                         const int* __restrict__ rowptr, int* __restrict__ fill,
                         const float* __restrict__ dis,
                         uint2* __restrict__ erec, int E) {
    int e = blockIdx.x * 256 + threadIdx.x;
    if (e >= E) return;
    int d = dst[e], s = src[e];
    int old = atomicSub(&fill[d], 1);
    int pos = rowptr[d] + old - 1;
    float c = dis[s] * dis[d];
    uint2 r; r.x = (unsigned)s; r.y = __builtin_bit_cast(unsigned, c);
    erec[pos] = r;
}

// ================= mm layer1 (K=256): W in REGISTERS, cooperative bf16 A staging ======
__global__ __launch_bounds__(256) void mm1scanCK(const void* __restrict__ x,
                                                 const ushort_t* __restrict__ Wt1,
                                                 ushort_t* __restrict__ tbuf, int n,
                                                 const ushort_t* __restrict__ flagRef,
                                                 const int* __restrict__ cnt,
                                                 const int* __restrict__ partial,
                                                 int* __restrict__ rowptr, int nbScan) {
    __shared__ char smem[33792];           // 2 x 16KB A bufs | scanC scratch (1KB)
    const int tid = threadIdx.x;
    if ((int)blockIdx.x < nbScan) {
        scanC2Dev((int*)smem, cnt, partial, rowptr, n, blockIdx.x, nbScan);
        return;
    }
    const int arm = blockIdx.x - nbScan;
    const int NB  = gridDim.x - nbScan;
    const int nTiles = (n + MTILE - 1) / MTILE;
    if (arm >= nTiles) return;

    const int lane = tid & 63, wave = tid >> 6;
    const int m = lane & 15, q = lane >> 4;
    const int flag = (flagRef[0] == 0x3F80) ? 1 : 0;

    // ---- W fragments in registers: wave w covers out-ch groups t = 2w, 2w+1
    ushort8 wfrag[8][2];
#pragma unroll
    for (int s = 0; s < 8; ++s)
#pragma unroll
        for (int tt = 0; tt < 2; ++tt)
            wfrag[s][tt] = *(const ushort8*)&Wt1[(size_t)((wave * 2 + tt) * 16 + m) * 256 + s * 32 + q * 8];

    // staging thread mapping: row sr (0..31), 32 cols starting at sa*32
    const int sr = tid >> 3, sa = tid & 7;
    char* buf0 = smem;
    char* buf1 = smem + 16384;

    float4  f[8];
    ushort8 v[4];

    auto stageLoad = [&](int T) {
        int row = T * MTILE + sr; if (row >= n) row = n - 1;
        if (flag) {
            const ushort_t* xp = (const ushort_t*)x + (size_t)row * 256 + sa * 32;
#pragma unroll
            for (int j = 0; j < 4; ++j) v[j] = *(const ushort8*)(xp + j * 8);
        } else {
            const float* xp = (const float*)x + (size_t)row * 256 + sa * 32;
#pragma unroll
            for (int j = 0; j < 8; ++j) f[j] = *(const float4*)(xp + j * 4);
        }
    };
    auto convWrite = [&](char* buf) {
        if (!flag) {
#pragma unroll
            for (int j = 0; j < 4; ++j) {
                float4 a = f[2 * j], b = f[2 * j + 1];
                ushort8 t8;
                t8[0] = f2bf(a.x); t8[1] = f2bf(a.y); t8[2] = f2bf(a.z); t8[3] = f2bf(a.w);
                t8[4] = f2bf(b.x); t8[5] = f2bf(b.y); t8[6] = f2bf(b.z); t8[7] = f2bf(b.w);
                v[j] = t8;
            }
        }
#pragma unroll
        for (int j = 0; j < 4; ++j) {
            int u = (sa * 4 + j) ^ (sr & 7);
            *(ushort8*)(buf + sr * 512 + u * 16) = v[j];
        }
    };
    auto computeStore = [&](int T, const char* buf) {
        f32x4 acc[2][2];
#pragma unroll
        for (int bb = 0; bb < 2; ++bb)
#pragma unroll
            for (int tt = 0; tt < 2; ++tt) acc[bb][tt] = (f32x4){0.f, 0.f, 0.f, 0.f};
#pragma unroll
        for (int bb = 0; bb < 2; ++bb) {
            const char* base = buf + (bb * 16 + m) * 512;
#pragma unroll
            for (int s = 0; s < 8; ++s) {
                ushort8 xf = *(const ushort8*)(base + (((s * 4 + q) ^ (m & 7)) * 16));
                bf16x8 xb = __builtin_bit_cast(bf16x8, xf);
#pragma unroll
                for (int tt = 0; tt < 2; ++tt)
                    acc[bb][tt] = __builtin_amdgcn_mfma_f32_16x16x32_bf16(
                        __builtin_bit_cast(bf16x8, wfrag[s][tt]), xb, acc[bb][tt], 0, 0, 0);
            }
        }
#pragma unroll
        for (int bb = 0; bb < 2; ++bb) {
            int node = T * MTILE + bb * 16 + m;
            if (node < n) {
#pragma unroll
                for (int tt = 0; tt < 2; ++tt) {
                    ushort4v pk;
#pragma unroll
                    for (int r = 0; r < 4; ++r) pk[r] = f2bf(acc[bb][tt][r]);
                    *(ushort4v*)(tbuf + (size_t)node * HH + (wave * 2 + tt) * 16 + q * 4) = pk;
                }
            }
        }
    };

    // prologue
    stageLoad(arm); convWrite(buf0);
    __syncthreads();
    int T = arm, pp = 0;
    while (true) {
        int Tn = T + NB;
        bool more = (Tn < nTiles);
        if (more) stageLoad(Tn);               // issue next-tile loads early
        computeStore(T, pp ? buf1 : buf0);     // hide load latency under MFMAs
        if (!more) break;
        convWrite(pp ? buf0 : buf1);
        __syncthreads();
        T = Tn; pp ^= 1;
    }
}

// ================= mmBN (K=128, full 128ch): W 32KB + A 16KB + scw -> 3 blocks/CU ======
__global__ __launch_bounds__(256) void mmBNK(const ushort_t* __restrict__ A,
                                             const ushort_t* __restrict__ Wt,
                                             ushort_t* __restrict__ out, int n,
                                             const float* __restrict__ ssum,
                                             const float* __restrict__ ssq,
                                             const float* __restrict__ gam,
                                             const float* __restrict__ bet) {
    __shared__ char smem[50176];           // W 32768 | A 16384 | scw 1024
    char* abuf = smem + 32768;
    float* scw = (float*)(smem + 49152);
    const int tid = threadIdx.x;

    if (tid < 128) {
        float S = 0.f, Q = 0.f;
#pragma unroll
        for (int sl = 0; sl < STAT_SLICES; ++sl) { S += ssum[sl * HH + tid]; Q += ssq[sl * HH + tid]; }
        float invn = 1.0f / (float)n;
        float mu = S * invn;
        float var = fmaxf(Q * invn - mu * mu, 0.f);
        float sc = gam[tid] * rsqrtf(var + EPS);
        scw[tid] = sc;
        scw[128 + tid] = bet[tid] - mu * sc;
    }
#pragma unroll
    for (int it = 0; it < 8; ++it) {
        int idx = tid + it * 256;          // 0..2047 = 128 rows x 16 segs
        int r = idx >> 4, seg = idx & 15;
        int p = seg ^ (r & 7);
        *(uint4*)&smem[r * 256 + p * 16] = *(const uint4*)&Wt[(size_t)r * 128 + seg * 8];
    }
    __syncthreads();

    const int lane = tid & 63, wave = tid >> 6;
    const int m = lane & 15, q = lane >> 4;
    const int nTiles = (n + 63) >> 6;

    for (int tile = blockIdx.x; tile < nTiles; tile += gridDim.x) {
        const int row0 = tile * 64 + wave * 16;
        // 4 DMA instrs: rows row0+4j .. +4 (1KB each, 256B rows)
#pragma unroll
        for (int j = 0; j < 4; ++j) {
            int r = row0 + j * 4;
            if (r + 3 >= n) r = n - 4;
            const char* g = (const char*)A + (size_t)r * 256 + lane * 16;
            dma16(g, abuf + (wave * 16 + j * 4) * 256);
        }
        __builtin_amdgcn_s_waitcnt(0x0F70);   // vmcnt(0)

        f32x4 acc[8];
#pragma unroll
        for (int t = 0; t < 8; ++t) acc[t] = (f32x4){0.f, 0.f, 0.f, 0.f};
        const char* arow = abuf + (wave * 16 + m) * 256;
#pragma unroll
        for (int s = 0; s < 4; ++s) {
            ushort8 av = *(const ushort8*)(arow + s * 64 + q * 16);
            int kb = s * 32 + q * 8;
#pragma unroll
            for (int j = 0; j < 8; ++j)
                av[j] = f2bf(fmaxf(bf2f(av[j]) * scw[kb + j] + scw[128 + kb + j], 0.f));
            bf16x8 nf = __builtin_bit_cast(bf16x8, av);
#pragma unroll
            for (int t = 0; t < 8; ++t) {
                int p = (s * 4 + q) ^ (m & 7);
                ushort8 wv = *(const ushort8*)&smem[(t * 16 + m) * 256 + p * 16];
                acc[t] = __builtin_amdgcn_mfma_f32_16x16x32_bf16(
                    __builtin_bit_cast(bf16x8, wv), nf, acc[t], 0, 0, 0);
            }
        }
        int node = tile * 64 + wave * 16 + m;
        if (node < n) {
            ushort_t* op = out + (size_t)node * HH + q * 4;
#pragma unroll
            for (int t = 0; t < 8; ++t) {
                ushort4v pk;
#pragma unroll
                for (int r = 0; r < 4; ++r) pk[r] = f2bf(acc[t][r]);
                *(ushort4v*)(op + t * 16) = pk;
            }
        }
    }
}

// ================= aggregation + bias + fused BN stats ==================================
// 4 nodes/wave (16 lanes/node, 8 ch/lane). Edge segments are PADDED to multiples of 8
// (pad records src=0/coef=0, L1-hot) -> single unguarded 8-edge inner loop, no tail,
// no per-node branch.
__global__ __launch_bounds__(256) void aggK(const ushort_t* __restrict__ t,
                                            const uint2* __restrict__ erec,
                                            const int* __restrict__ rowptr,
                                            const float* __restrict__ dis,
                                            const float* __restrict__ bias,
                                            ushort_t* __restrict__ g,
                                            float* __restrict__ ssum, float* __restrict__ ssq,
                                            int n) {
    const int tid  = threadIdx.x;
    const int lane = tid & 63;
    const int wave = tid >> 6;
    const int grp  = lane >> 4;            // 0..3: node slot within wave
    const int p    = lane & 15;            // channel slot: channels p*8 .. p*8+7
    const int cb   = p * 8;

    float bch[8];
#pragma unroll
    for (int j = 0; j < 8; ++j) bch[j] = bias[cb + j];

    float s[8], q[8];
#pragma unroll
    for (int j = 0; j < 8; ++j) { s[j] = 0.f; q[j] = 0.f; }

    for (int node = blockIdx.x * 16 + wave * 4 + grp; node < n; node += gridDim.x * 16) {
        float d = dis[node];
        float d2 = d * d;
        float a[8];
#pragma unroll
        for (int j = 0; j < 8; ++j) a[j] = 0.f;
        // self-loop term
        uint4 sv = *(const uint4*)(t + (size_t)node * HH + cb);
        acc8(sv, d2, a);

        const int beg = rowptr[node], end = rowptr[node + 1];
        for (int e = beg; e < end; e += 8) {            // end-beg is a multiple of 8
            uint2 rr[8];
#pragma unroll
            for (int kk = 0; kk < 8; ++kk) rr[kk] = erec[e + kk];   // group-broadcast
            uint4 w0[4];
#pragma unroll
            for (int kk = 0; kk < 4; ++kk)
                w0[kk] = *(const uint4*)(t + (size_t)rr[kk].x * HH + cb);
            uint4 w1[4];
#pragma unroll
            for (int kk = 0; kk < 4; ++kk)
                w1[kk] = *(const uint4*)(t + (size_t)rr[4 + kk].x * HH + cb);
#pragma unroll
            for (int kk = 0; kk < 4; ++kk)
                acc8(w0[kk], __builtin_bit_cast(float, rr[kk].y), a);
#pragma unroll
            for (int kk = 0; kk < 4; ++kk)
                acc8(w1[kk], __builtin_bit_cast(float, rr[4 + kk].y), a);
        }

        ushort8 pk;
#pragma unroll
        for (int j = 0; j < 8; ++j) {
            a[j] += bch[j];
            pk[j] = f2bf(a[j]);
            s[j] += a[j]; q[j] += a[j] * a[j];
        }
        *(ushort8*)(g + (size_t)node * HH + cb) = pk;      // 16B/lane, 256B/group burst
    }

    // reduce across the 4 groups (lanes p, p+16, p+32, p+48 hold same channels)
#pragma unroll
    for (int j = 0; j < 8; ++j) {
        s[j] += __shfl_xor(s[j], 16); s[j] += __shfl_xor(s[j], 32);
        q[j] += __shfl_xor(q[j], 16); q[j] += __shfl_xor(q[j], 32);
    }
    __shared__ float red[4][16][16];
    if (grp == 0) {
#pragma unroll
        for (int j = 0; j < 8; ++j) { red[wave][p][j] = s[j]; red[wave][p][8 + j] = q[j]; }
    }
    __syncthreads();
    {
        int ch = tid & 127, kind = tid >> 7;               // 256 threads -> 256 atomics
        float S = 0.f;
#pragma unroll
        for (int w = 0; w < 4; ++w) S += red[w][ch >> 3][kind * 8 + (ch & 7)];
        int slice = (blockIdx.x & (STAT_SLICES - 1)) * HH;
        atomicAdd((kind ? ssq : ssum) + slice + ch, S);
    }
}

// ================= final head: inline stats finalize + relu(bn(g)) @ Wf + bf ===========
__global__ __launch_bounds__(256) void outK(const ushort_t* __restrict__ g,
                                            const float* __restrict__ ssum,
                                            const float* __restrict__ ssq,
                                            const float* __restrict__ gam,
                                            const float* __restrict__ bet,
                                            const float* __restrict__ Wf,
                                            const float* __restrict__ bfp,
                                            void* __restrict__ outv, int n,
                                            const ushort_t* __restrict__ flagRef) {
    __shared__ float scw[256];
    const int tid = threadIdx.x;
    if (tid < 128) {
        float S = 0.f, Q = 0.f;
#pragma unroll
        for (int sl = 0; sl < STAT_SLICES; ++sl) { S += ssum[sl * HH + tid]; Q += ssq[sl * HH + tid]; }
        float invn = 1.0f / (float)n;
        float mu = S * invn;
        float var = fmaxf(Q * invn - mu * mu, 0.f);
        float sc = gam[tid] * rsqrtf(var + EPS);
        scw[tid] = sc;
        scw[128 + tid] = bet[tid] - mu * sc;
    }
    __syncthreads();

    const int lane = tid & 63;
    const int wave = tid >> 6;
    const int grp  = lane >> 4;
    const int p    = lane & 15;
    const int cb   = p * 8;
    float w8[8], sc8[8], sh8[8];
#pragma unroll
    for (int j = 0; j < 8; ++j) {
        w8[j] = Wf[cb + j]; sc8[j] = scw[cb + j]; sh8[j] = scw[128 + cb + j];
    }
    const float bb = bfp[0];
    const int flag = (flagRef[0] == 0x3F80) ? 1 : 0;

    for (int node = blockIdx.x * 16 + wave * 4 + grp; node < n; node += gridDim.x * 16) {
        uint4 v = *(const uint4*)(g + (size_t)node * HH + cb);
        unsigned u[4] = {v.x, v.y, v.z, v.w};
        float x = 0.f;
#pragma unroll
        for (int j = 0; j < 4; ++j) {
            float f0 = __builtin_bit_cast(float, u[j] << 16);
            float f1 = __builtin_bit_cast(float, u[j] & 0xffff0000u);
            x += fmaxf(f0 * sc8[2 * j] + sh8[2 * j], 0.f) * w8[2 * j];
            x += fmaxf(f1 * sc8[2 * j + 1] + sh8[2 * j + 1], 0.f) * w8[2 * j + 1];
        }
#pragma unroll
        for (int off = 8; off; off >>= 1) x += __shfl_xor(x, off);   // within 16-lane group
        if (p == 0) {
            float r = x + bb;
            if (flag) ((ushort_t*)outv)[node] = f2bf(r);
            else      ((float*)outv)[node] = r;
        }
    }
}

// ================= launch =================
extern "C" void kernel_launch(void* const* d_in, const int* in_sizes, int n_in,
                              void* d_out, int out_size, void* d_ws, size_t ws_size,
                              hipStream_t stream) {
    const int DIN = 256;
    const int N = in_sizes[0] / DIN;
    const int E = in_sizes[1];

    const void* x   = d_in[0];
    const int*  src = (const int*)d_in[1];
    const int*  dst = (const int*)d_in[2];
    const void* W1  = d_in[3];
    const void* b1  = d_in[4];
    const void* g1  = d_in[5];
    const void* be1 = d_in[6];
    const void* W2  = d_in[7];
    const void* b2  = d_in[8];
    const void* g2  = d_in[9];
    const void* be2 = d_in[10];
    const void* W3  = d_in[11];
    const void* b3  = d_in[12];
    const void* g3  = d_in[13];
    const void* be3 = d_in[14];
    const void* Wf  = d_in[15];
    const void* bfp = d_in[16];
    const ushort_t* flagRef = (const ushort_t*)g1;

    char* base = (char*)d_ws;
    size_t off = 0;
    auto carve = [&](size_t bytes) -> void* {
        void* p = base + off;
        off += (bytes + 255) & ~(size_t)255;
        return p;
    };
    // zeroed prefix: counts | stats | erec (erec pad slots must read as src=0/coef=0)
    int*      counts = (int*)carve((size_t)N * 4);
    float*    stats  = (float*)carve((size_t)3 * 2 * STAT_SLICES * HH * 4);
    uint2*    erec   = (uint2*)carve(((size_t)E + 7 * (size_t)N) * 8);
    size_t    zbytes = off;                       // memset range [0, zbytes)
    float*    dis    = (float*)carve((size_t)N * 4);
    int*      rowptr = (int*)carve((size_t)(N + 1) * 4);
    int*      partial= (int*)carve(256 * 4);
    ushort_t* Wt1    = (ushort_t*)carve((size_t)128 * 256 * 2);
    ushort_t* Wt2    = (ushort_t*)carve((size_t)128 * 128 * 2);
    ushort_t* Wt3    = (ushort_t*)carve((size_t)128 * 128 * 2);
    ushort_t* tbuf   = (ushort_t*)carve((size_t)N * HH * 2);
    ushort_t* gbuf   = (ushort_t*)carve((size_t)N * HH * 2);
    float*    cvec   = (float*)carve((size_t)1281 * 4);

    float* ssum0 = stats;                         float* ssq0 = ssum0 + STAT_SLICES * HH;
    float* ssum1 = ssq0 + STAT_SLICES * HH;       float* ssq1 = ssum1 + STAT_SLICES * HH;
    float* ssum2 = ssq1 + STAT_SLICES * HH;       float* ssq2 = ssum2 + STAT_SLICES * HH;

    float* c_b1 = cvec;         float* c_b2 = cvec + 128;  float* c_b3 = cvec + 256;
    float* c_g1 = cvec + 384;   float* c_g2 = cvec + 512;  float* c_g3 = cvec + 640;
    float* c_be1 = cvec + 768;  float* c_be2 = cvec + 896; float* c_be3 = cvec + 1024;
    float* c_Wf = cvec + 1152;  float* c_bf = cvec + 1280;

    const int nbScan = (N + 2047) / 2048;
    const int histB  = (E + 255) / 256;
    const int disB   = (N + 255) / 256;
    const int aggB   = 2048;
    const int mm1B   = 1024;

    hipMemsetAsync(d_ws, 0, zbytes, stream);   // counts + stats + erec (pad slots)

    preK<<<histB + 256 + 1, 256, 0, stream>>>(dst, counts, E, W1, Wt1, W2, Wt2, W3, Wt3,
                                              g1, b1, b2, b3, g2, g3, be1, be2, be3, Wf, bfp,
                                              cvec, histB);
    scanAdisK<<<nbScan + disB, 256, 0, stream>>>(counts, partial, dis, N, nbScan);
    mm1scanCK<<<nbScan + mm1B, 256, 0, stream>>>(x, Wt1, tbuf, N, flagRef,
                                                 counts, partial, rowptr, nbScan);
    scatterK<<<histB, 256, 0, stream>>>(src, dst, rowptr, counts, dis, erec, E);

    aggK<<<aggB, 256, 0, stream>>>(tbuf, erec, rowptr, dis, c_b1, gbuf, ssum0, ssq0, N);
    mmBNK<<<768, 256, 0, stream>>>(gbuf, Wt2, tbuf, N, ssum0, ssq0, c_g1, c_be1);
    aggK<<<aggB, 256, 0, stream>>>(tbuf, erec, rowptr, dis, c_b2, gbuf, ssum1, ssq1, N);
    mmBNK<<<768, 256, 0, stream>>>(gbuf, Wt3, tbuf, N, ssum1, ssq1, c_g2, c_be2);
    aggK<<<aggB, 256, 0, stream>>>(tbuf, erec, rowptr, dis, c_b3, gbuf, ssum2, ssq2, N);
    outK<<<1024, 256, 0, stream>>>(gbuf, ssum2, ssq2, c_g3, c_be3, c_Wf, c_bf, d_out, N, flagRef);
}